// Round 5
// baseline (194.002 us; speedup 1.0000x reference)
//
#include <hip/hip_runtime.h>
#include <cstdint>
#include <cmath>

#define B_   8
#define L_   1024
#define DM_  256
#define DS_  16
#define DC_  4
#define DI_  512
#define DTR_ 16
#define M_   (B_*L_)    // 8192
#define NCH  32         // number of scan chunks
#define CH   32         // chunk length (NCH*CH == L_)

using half8 = __attribute__((ext_vector_type(8))) _Float16;
using f32x4 = __attribute__((ext_vector_type(4))) float;

// ---------------------------------------------------------------------------
// load 8 contiguous elements as fp16, converting from fp32 if F32
// ---------------------------------------------------------------------------
template<bool F32>
__device__ __forceinline__ half8 load_h8(const void* base, size_t off)
{
    if constexpr (F32) {
        const float* p = (const float*)base + off;
        const float4 a = *reinterpret_cast<const float4*>(p);
        const float4 b = *reinterpret_cast<const float4*>(p + 4);
        half8 h;
        h[0] = (_Float16)a.x; h[1] = (_Float16)a.y;
        h[2] = (_Float16)a.z; h[3] = (_Float16)a.w;
        h[4] = (_Float16)b.x; h[5] = (_Float16)b.y;
        h[6] = (_Float16)b.z; h[7] = (_Float16)b.w;
        return h;
    } else {
        return *reinterpret_cast<const half8*>((const _Float16*)base + off);
    }
}

// ---------------------------------------------------------------------------
// fp16 MFMA GEMM: C[m,n] = act(sum_k A[m,k]*W[n,k] + bias[n])
// Tile BM=128, BN=128, BK=32; 256 threads = 4 waves (2x2), wave tile 64x64
// (4x4 fragments, 16 mfma_f32_16x16x32_f16 per K-step).
// A32/W32: source is fp32, converted during LDS staging.
// ---------------------------------------------------------------------------
template<int ACT, bool BIAS, bool OUTH, bool A32, bool W32>
__global__ __launch_bounds__(256)
void hgemm_k(const void* __restrict__ A, int lda,
             const void* __restrict__ W,
             const float* __restrict__ bias,
             void* __restrict__ Cv, int ldc, int K)
{
    __shared__ _Float16 Ash[128][40];
    __shared__ _Float16 Bsh[128][40];
    const int tid  = threadIdx.x;
    const int lane = tid & 63;
    const int w    = tid >> 6;
    const int wm   = (w >> 1) * 64;
    const int wn   = (w & 1) * 64;
    const int bm   = blockIdx.x * 128;
    const int bn   = blockIdx.y * 128;

    const int fr = lane & 15;
    const int fk = (lane >> 4) * 8;
    const int sr = tid >> 2;
    const int sg = (tid & 3) * 8;

    f32x4 acc[4][4] = {};

    for (int k0 = 0; k0 < K; k0 += 32) {
        *reinterpret_cast<half8*>(&Ash[sr][sg]) =
            load_h8<A32>(A, (size_t)(bm + sr) * lda + k0 + sg);
        *reinterpret_cast<half8*>(&Ash[sr + 64][sg]) =
            load_h8<A32>(A, (size_t)(bm + sr + 64) * lda + k0 + sg);
        *reinterpret_cast<half8*>(&Bsh[sr][sg]) =
            load_h8<W32>(W, (size_t)(bn + sr) * K + k0 + sg);
        *reinterpret_cast<half8*>(&Bsh[sr + 64][sg]) =
            load_h8<W32>(W, (size_t)(bn + sr + 64) * K + k0 + sg);
        __syncthreads();

        half8 af[4], bf[4];
        #pragma unroll
        for (int mf = 0; mf < 4; mf++)
            af[mf] = *reinterpret_cast<const half8*>(&Ash[wm + mf * 16 + fr][fk]);
        #pragma unroll
        for (int nf = 0; nf < 4; nf++)
            bf[nf] = *reinterpret_cast<const half8*>(&Bsh[wn + nf * 16 + fr][fk]);
        #pragma unroll
        for (int mf = 0; mf < 4; mf++)
            #pragma unroll
            for (int nf = 0; nf < 4; nf++)
                acc[mf][nf] = __builtin_amdgcn_mfma_f32_16x16x32_f16(
                    af[mf], bf[nf], acc[mf][nf], 0, 0, 0);
        __syncthreads();
    }

    const int orow = (lane >> 4) * 4;
    const int ocol = lane & 15;
    #pragma unroll
    for (int mf = 0; mf < 4; mf++) {
        #pragma unroll
        for (int nf = 0; nf < 4; nf++) {
            const int gc = bn + wn + nf * 16 + ocol;
            float b = BIAS ? bias[gc] : 0.f;
            #pragma unroll
            for (int r = 0; r < 4; r++) {
                const int gr = bm + wm + mf * 16 + orow + r;
                float v = acc[mf][nf][r] + b;
                if (ACT == 1) v = fmaxf(v, 0.f);
                if (OUTH)
                    ((_Float16*)Cv)[(size_t)gr * ldc + gc] = (_Float16)v;
                else
                    ((float*)Cv)[(size_t)gr * ldc + gc] = v;
            }
        }
    }
}

// ---------------------------------------------------------------------------
// x_proj MFMA kernel: xs (M,512) fp32 -> split x_dbl outputs.
// BM=64, BN=48 (3 fragments), BK=32; fp32->fp16 fused into staging.
// cols 0..15 -> dtr32 (M,16) ; cols 16..47 -> xdbl32 (M,32)  (B,C)
// ---------------------------------------------------------------------------
__global__ __launch_bounds__(256)
void xproj_k(const float* __restrict__ xs,
             const float* __restrict__ xpw,
             float* __restrict__ dtr32,
             float* __restrict__ xdbl32)
{
    __shared__ _Float16 Ash[64][40];
    __shared__ _Float16 Bsh[48][40];
    const int tid  = threadIdx.x;
    const int lane = tid & 63;
    const int w    = tid >> 6;
    const int bm   = blockIdx.x * 64;
    const int fr   = lane & 15;
    const int fk   = (lane >> 4) * 8;
    const int sr   = tid >> 2;
    const int sg   = (tid & 3) * 8;

    f32x4 acc[3] = {};

    for (int k0 = 0; k0 < 512; k0 += 32) {
        *reinterpret_cast<half8*>(&Ash[sr][sg]) =
            load_h8<true>(xs, (size_t)(bm + sr) * 512 + k0 + sg);
        if (sr < 48)
            *reinterpret_cast<half8*>(&Bsh[sr][sg]) =
                load_h8<true>(xpw, (size_t)sr * 512 + k0 + sg);
        __syncthreads();
        const half8 af = *reinterpret_cast<const half8*>(&Ash[w * 16 + fr][fk]);
        #pragma unroll
        for (int nf = 0; nf < 3; nf++) {
            const half8 bf = *reinterpret_cast<const half8*>(&Bsh[nf * 16 + fr][fk]);
            acc[nf] = __builtin_amdgcn_mfma_f32_16x16x32_f16(af, bf, acc[nf], 0, 0, 0);
        }
        __syncthreads();
    }

    const int orow = (lane >> 4) * 4;
    const int ocol = lane & 15;
    #pragma unroll
    for (int nf = 0; nf < 3; nf++) {
        #pragma unroll
        for (int r = 0; r < 4; r++) {
            const int gr = bm + w * 16 + orow + r;
            const float v = acc[nf][r];
            if (nf == 0)
                dtr32[(size_t)gr * 16 + ocol] = v;
            else
                xdbl32[(size_t)gr * 32 + (nf - 1) * 16 + ocol] = v;
        }
    }
}

// ---------------------------------------------------------------------------
// (R,C) row-major -> (C,R) row-major transpose + fp32->fp16 (small weights)
// ---------------------------------------------------------------------------
__global__ __launch_bounds__(256)
void cvtT_f2h(const float* __restrict__ in, _Float16* __restrict__ out, int R, int C)
{
    const int g = blockIdx.x * 256 + threadIdx.x;
    if (g < R * C) {
        const int r = g / C, c = g - r * C;
        out[(size_t)c * R + r] = (_Float16)in[g];
    }
}

// ---------------------------------------------------------------------------
// Causal depthwise conv (DC=4 taps) + SiLU.  x lives in xz[:, 0:DI].
// ---------------------------------------------------------------------------
__global__ __launch_bounds__(256)
void conv_silu_k(const float* __restrict__ xz, const float* __restrict__ cw,
                 const float* __restrict__ cb, float* __restrict__ xs)
{
    const int gid = blockIdx.x * 256 + threadIdx.x;
    const int d   = gid & (DI_ - 1);
    const int row = gid >> 9;
    const int t   = row & (L_ - 1);
    float acc = cb[d];
    #pragma unroll
    for (int k = 0; k < DC_; k++) {
        const int tt = t - (DC_ - 1) + k;
        if (tt >= 0)
            acc += xz[(size_t)(row - (DC_ - 1) + k) * (2 * DI_) + d] * cw[d * DC_ + k];
    }
    xs[(size_t)row * DI_ + d] = acc * (1.f / (1.f + __expf(-acc)));
}

// ---------------------------------------------------------------------------
// Scan phase 1: dt computed inline (softplus(dtr . dtw_row + b)).
// ---------------------------------------------------------------------------
__global__ __launch_bounds__(512)
void scan_phase1(const float* __restrict__ dtr32, const float* __restrict__ dtw,
                 const float* __restrict__ dtb, const float* __restrict__ xs,
                 const float* __restrict__ xdbl32, const float* __restrict__ A_log,
                 float* __restrict__ h_end, float* __restrict__ dtsum)
{
    const int c = blockIdx.x, b = blockIdx.y, d = threadIdx.x;
    __shared__ float Bs[CH][DS_];
    __shared__ float Dtr[CH][DTR_];
    {
        const int tl = threadIdx.x >> 4, n = threadIdx.x & 15;
        const size_t row = (size_t)(b * L_ + c * CH + tl);
        Bs[tl][n]  = xdbl32[row * 32 + n];
        Dtr[tl][n] = dtr32[row * 16 + n];
    }
    __syncthreads();
    float Av[DS_], wreg[DTR_];
    #pragma unroll
    for (int n = 0; n < DS_; n++) Av[n] = -expf(A_log[d * DS_ + n]);
    #pragma unroll
    for (int r = 0; r < DTR_; r++) wreg[r] = dtw[d * DTR_ + r];
    const float bd = dtb[d];
    float h[DS_] = {};
    float dts = 0.f;
    const int base = b * L_ + c * CH;
    for (int tl = 0; tl < CH; tl++) {
        float v = bd;
        #pragma unroll
        for (int r = 0; r < DTR_; r++) v += Dtr[tl][r] * wreg[r];
        const float dtv = (v > 20.f) ? v : log1pf(__expf(v));
        const float xv  = xs[(size_t)(base + tl) * DI_ + d];
        dts += dtv;
        const float dtx = dtv * xv;
        #pragma unroll
        for (int n = 0; n < DS_; n++)
            h[n] = __expf(dtv * Av[n]) * h[n] + dtx * Bs[tl][n];
    }
    const size_t o = (size_t)(b * NCH + c) * DI_ + d;
    #pragma unroll
    for (int n = 0; n < DS_; n++) h_end[o * DS_ + n] = h[n];
    dtsum[o] = dts;
}

// ---------------------------------------------------------------------------
// Scan phase 2: sequential combine across chunks.
// ---------------------------------------------------------------------------
__global__ __launch_bounds__(256)
void scan_phase2(const float* __restrict__ h_end, const float* __restrict__ dtsum,
                 const float* __restrict__ A_log, float* __restrict__ h_start)
{
    const int gid = blockIdx.x * 256 + threadIdx.x;
    const int n = gid & 15;
    const int d = (gid >> 4) & (DI_ - 1);
    const int b = gid >> 13;
    const float Av = -expf(A_log[d * DS_ + n]);
    float hs = 0.f;
    for (int c = 0; c < NCH; c++) {
        const size_t o = (size_t)(b * NCH + c) * DI_ + d;
        h_start[o * DS_ + n] = hs;
        hs = __expf(Av * dtsum[o]) * hs + h_end[o * DS_ + n];
    }
}

// ---------------------------------------------------------------------------
// Scan phase 3: replay with incoming h_start, dt inline, emit y fp16.
// ---------------------------------------------------------------------------
__global__ __launch_bounds__(512)
void scan_phase3(const float* __restrict__ dtr32, const float* __restrict__ dtw,
                 const float* __restrict__ dtb, const float* __restrict__ xs,
                 const float* __restrict__ xdbl32, const float* __restrict__ A_log,
                 const float* __restrict__ Dv, const float* __restrict__ xz,
                 const float* __restrict__ h_start, _Float16* __restrict__ yout)
{
    const int c = blockIdx.x, b = blockIdx.y, d = threadIdx.x;
    __shared__ float Bs[CH][DS_];
    __shared__ float Cs[CH][DS_];
    __shared__ float Dtr[CH][DTR_];
    {
        const int tl = threadIdx.x >> 4, n = threadIdx.x & 15;
        const size_t row = (size_t)(b * L_ + c * CH + tl);
        Bs[tl][n]  = xdbl32[row * 32 + n];
        Cs[tl][n]  = xdbl32[row * 32 + 16 + n];
        Dtr[tl][n] = dtr32[row * 16 + n];
    }
    __syncthreads();
    float Av[DS_], wreg[DTR_];
    #pragma unroll
    for (int n = 0; n < DS_; n++) Av[n] = -expf(A_log[d * DS_ + n]);
    #pragma unroll
    for (int r = 0; r < DTR_; r++) wreg[r] = dtw[d * DTR_ + r];
    const float bd = dtb[d];
    float h[DS_];
    const size_t o = ((size_t)(b * NCH + c) * DI_ + d) * DS_;
    #pragma unroll
    for (int n = 0; n < DS_; n++) h[n] = h_start[o + n];
    const float Dd = Dv[d];
    const int base = b * L_ + c * CH;
    for (int tl = 0; tl < CH; tl++) {
        const size_t ro = (size_t)(base + tl);
        float v = bd;
        #pragma unroll
        for (int r = 0; r < DTR_; r++) v += Dtr[tl][r] * wreg[r];
        const float dtv = (v > 20.f) ? v : log1pf(__expf(v));
        const float xv  = xs[ro * DI_ + d];
        const float dtx = dtv * xv;
        float acc = 0.f;
        #pragma unroll
        for (int n = 0; n < DS_; n++) {
            h[n] = __expf(dtv * Av[n]) * h[n] + dtx * Bs[tl][n];
            acc += h[n] * Cs[tl][n];
        }
        const float yv = acc + xv * Dd;
        const float zv = xz[ro * (2 * DI_) + DI_ + d];
        const float g  = zv * (1.f / (1.f + __expf(-zv)));
        yout[ro * DI_ + d] = (_Float16)(yv * g);
    }
}

// ---------------------------------------------------------------------------
// Final N=1 GEMV
// ---------------------------------------------------------------------------
__global__ __launch_bounds__(256)
void final_dot(const float* __restrict__ h2, const float* __restrict__ w3,
               const float* __restrict__ b3, float* __restrict__ out)
{
    __shared__ float w3s[128];
    const int tid = threadIdx.x;
    if (tid < 128) w3s[tid] = w3[tid];
    __syncthreads();
    const int m = blockIdx.x * 256 + tid;
    float acc = b3[0];
    #pragma unroll 4
    for (int k = 0; k < 128; k++) acc += h2[(size_t)m * 128 + k] * w3s[k];
    out[m] = acc;
}

// ---------------------------------------------------------------------------
extern "C" void kernel_launch(void* const* d_in, const int* in_sizes, int n_in,
                              void* d_out, int out_size, void* d_ws, size_t ws_size,
                              hipStream_t stream)
{
    const float* state      = (const float*)d_in[0];
    const float* in_proj_w  = (const float*)d_in[1];
    const float* conv_w     = (const float*)d_in[2];
    const float* conv_b     = (const float*)d_in[3];
    const float* x_proj_w   = (const float*)d_in[4];
    const float* dt_proj_w  = (const float*)d_in[5];
    const float* dt_proj_b  = (const float*)d_in[6];
    const float* A_log      = (const float*)d_in[7];
    const float* Dp         = (const float*)d_in[8];
    const float* out_proj_w = (const float*)d_in[9];
    const float* w1 = (const float*)d_in[10];
    const float* b1 = (const float*)d_in[11];
    const float* w2 = (const float*)d_in[12];
    const float* b2 = (const float*)d_in[13];
    const float* w3 = (const float*)d_in[14];
    const float* b3 = (const float*)d_in[15];

    float* ws      = (float*)d_ws;
    float* xz      = ws;                          // 8,388,608 f  (32 MB)
    float* xs      = xz + 8388608;                // 4,194,304 f
    float* xdbl32  = xs + 4194304;                //   262,144 f
    float* dtr32   = xdbl32 + 262144;             //   131,072 f
    float* h_end   = dtr32 + 131072;              // 2,097,152 f
    float* dtsum   = h_end + 2097152;             //   131,072 f
    float* h_start = dtsum + 131072;              // 2,097,152 f
    _Float16* y_h  = (_Float16*)(h_start + 2097152); // 4,194,304 h (8 MB: M_*DI_)
    _Float16* w1t  = y_h + 4194304;               //    65,536 h  (AFTER y_h's full extent)
    _Float16* w2t  = w1t + 65536;                 //    32,768 h
    // tail buffers overlay xz (z is consumed by phase3 before these are written)
    _Float16* outb_h = (_Float16*)xz;             // 2,097,152 h
    _Float16* h1_h   = (_Float16*)(xz + 1048576); // 2,097,152 h
    float*    h2     = xz + 2097152;              // 1,048,576 f

    // 0. MLP weight transpose+convert (small)
    cvtT_f2h<<<dim3(256), 256, 0, stream>>>(w1, w1t, 256, 256);
    cvtT_f2h<<<dim3(128), 256, 0, stream>>>(w2, w2t, 256, 128);

    // 1. xz = state @ in_proj_w^T   (M=8192, N=1024, K=256), convert-on-stage
    hgemm_k<0, false, false, true, true><<<dim3(M_/128, 1024/128), 256, 0, stream>>>(
        state, DM_, in_proj_w, nullptr, xz, 2*DI_, DM_);
    // 2. causal conv + SiLU -> xs
    conv_silu_k<<<dim3(M_*DI_/256), 256, 0, stream>>>(xz, conv_w, conv_b, xs);
    // 3. x_dbl: MFMA fp16, split outputs (dtr32 / xdbl32)
    xproj_k<<<dim3(M_/64), 256, 0, stream>>>(xs, x_proj_w, dtr32, xdbl32);
    // 4-6. chunked selective scan (dt inline)
    scan_phase1<<<dim3(NCH, B_), 512, 0, stream>>>(
        dtr32, dt_proj_w, dt_proj_b, xs, xdbl32, A_log, h_end, dtsum);
    scan_phase2<<<dim3(256), 256, 0, stream>>>(h_end, dtsum, A_log, h_start);
    scan_phase3<<<dim3(NCH, B_), 512, 0, stream>>>(
        dtr32, dt_proj_w, dt_proj_b, xs, xdbl32, A_log, Dp, xz, h_start, y_h);
    // 7. out = y @ out_proj_w^T     (N=256, K=512), W convert-on-stage -> fp16
    hgemm_k<0, false, true, false, true><<<dim3(M_/128, 256/128), 256, 0, stream>>>(
        y_h, DI_, out_proj_w, nullptr, outb_h, DM_, DI_);
    // 8. h1 = relu(out @ w1 + b1)   (N=256, K=256) -> fp16
    hgemm_k<1, true, true, false, false><<<dim3(M_/128, 256/128), 256, 0, stream>>>(
        outb_h, DM_, w1t, b1, h1_h, 256, 256);
    // 9. h2 = relu(h1 @ w2 + b2)    (N=128, K=256) -> fp32
    hgemm_k<1, true, false, false, false><<<dim3(M_/128, 1), 256, 0, stream>>>(
        h1_h, 256, w2t, b2, h2, 128, 256);
    // 10. out = h2 @ w3 + b3        (N=1)
    final_dot<<<dim3(M_/256), 256, 0, stream>>>(h2, w3, b3, (float*)d_out);
}

// Round 6
// 185.968 us; speedup vs baseline: 1.0432x; 1.0432x over previous
//
#include <hip/hip_runtime.h>
#include <cstdint>
#include <cmath>

#define B_   8
#define L_   1024
#define DM_  256
#define DS_  16
#define DC_  4
#define DI_  512
#define DTR_ 16
#define M_   (B_*L_)    // 8192
#define NCH  64         // number of scan chunks (2 blocks/CU)
#define CH   16         // chunk length (NCH*CH == L_)

using half8 = __attribute__((ext_vector_type(8))) _Float16;
using f32x4 = __attribute__((ext_vector_type(4))) float;

// ---------------------------------------------------------------------------
// load 8 contiguous elements as fp16, converting from fp32 if F32
// ---------------------------------------------------------------------------
template<bool F32>
__device__ __forceinline__ half8 load_h8(const void* base, size_t off)
{
    if constexpr (F32) {
        const float* p = (const float*)base + off;
        const float4 a = *reinterpret_cast<const float4*>(p);
        const float4 b = *reinterpret_cast<const float4*>(p + 4);
        half8 h;
        h[0] = (_Float16)a.x; h[1] = (_Float16)a.y;
        h[2] = (_Float16)a.z; h[3] = (_Float16)a.w;
        h[4] = (_Float16)b.x; h[5] = (_Float16)b.y;
        h[6] = (_Float16)b.z; h[7] = (_Float16)b.w;
        return h;
    } else {
        return *reinterpret_cast<const half8*>((const _Float16*)base + off);
    }
}

// ---------------------------------------------------------------------------
// fp16 MFMA GEMM: C[m,n] = act(sum_k A[m,k]*W[n,k] + bias[n])
// Tile BM=128, BN=128, BK=32; 256 threads = 4 waves (2x2), wave tile 64x64.
// ---------------------------------------------------------------------------
template<int ACT, bool BIAS, bool OUTH, bool A32, bool W32>
__global__ __launch_bounds__(256)
void hgemm_k(const void* __restrict__ A, int lda,
             const void* __restrict__ W,
             const float* __restrict__ bias,
             void* __restrict__ Cv, int ldc, int K)
{
    __shared__ _Float16 Ash[128][40];
    __shared__ _Float16 Bsh[128][40];
    const int tid  = threadIdx.x;
    const int lane = tid & 63;
    const int w    = tid >> 6;
    const int wm   = (w >> 1) * 64;
    const int wn   = (w & 1) * 64;
    const int bm   = blockIdx.x * 128;
    const int bn   = blockIdx.y * 128;

    const int fr = lane & 15;
    const int fk = (lane >> 4) * 8;
    const int sr = tid >> 2;
    const int sg = (tid & 3) * 8;

    f32x4 acc[4][4] = {};

    for (int k0 = 0; k0 < K; k0 += 32) {
        *reinterpret_cast<half8*>(&Ash[sr][sg]) =
            load_h8<A32>(A, (size_t)(bm + sr) * lda + k0 + sg);
        *reinterpret_cast<half8*>(&Ash[sr + 64][sg]) =
            load_h8<A32>(A, (size_t)(bm + sr + 64) * lda + k0 + sg);
        *reinterpret_cast<half8*>(&Bsh[sr][sg]) =
            load_h8<W32>(W, (size_t)(bn + sr) * K + k0 + sg);
        *reinterpret_cast<half8*>(&Bsh[sr + 64][sg]) =
            load_h8<W32>(W, (size_t)(bn + sr + 64) * K + k0 + sg);
        __syncthreads();

        half8 af[4], bf[4];
        #pragma unroll
        for (int mf = 0; mf < 4; mf++)
            af[mf] = *reinterpret_cast<const half8*>(&Ash[wm + mf * 16 + fr][fk]);
        #pragma unroll
        for (int nf = 0; nf < 4; nf++)
            bf[nf] = *reinterpret_cast<const half8*>(&Bsh[wn + nf * 16 + fr][fk]);
        #pragma unroll
        for (int mf = 0; mf < 4; mf++)
            #pragma unroll
            for (int nf = 0; nf < 4; nf++)
                acc[mf][nf] = __builtin_amdgcn_mfma_f32_16x16x32_f16(
                    af[mf], bf[nf], acc[mf][nf], 0, 0, 0);
        __syncthreads();
    }

    const int orow = (lane >> 4) * 4;
    const int ocol = lane & 15;
    #pragma unroll
    for (int mf = 0; mf < 4; mf++) {
        #pragma unroll
        for (int nf = 0; nf < 4; nf++) {
            const int gc = bn + wn + nf * 16 + ocol;
            float b = BIAS ? bias[gc] : 0.f;
            #pragma unroll
            for (int r = 0; r < 4; r++) {
                const int gr = bm + wm + mf * 16 + orow + r;
                float v = acc[mf][nf][r] + b;
                if (ACT == 1) v = fmaxf(v, 0.f);
                if (OUTH)
                    ((_Float16*)Cv)[(size_t)gr * ldc + gc] = (_Float16)v;
                else
                    ((float*)Cv)[(size_t)gr * ldc + gc] = v;
            }
        }
    }
}

// ---------------------------------------------------------------------------
// x_proj MFMA kernel: xs (M,512) fp32 -> split x_dbl outputs.
// ---------------------------------------------------------------------------
__global__ __launch_bounds__(256)
void xproj_k(const float* __restrict__ xs,
             const float* __restrict__ xpw,
             float* __restrict__ dtr32,
             float* __restrict__ xdbl32)
{
    __shared__ _Float16 Ash[64][40];
    __shared__ _Float16 Bsh[48][40];
    const int tid  = threadIdx.x;
    const int lane = tid & 63;
    const int w    = tid >> 6;
    const int bm   = blockIdx.x * 64;
    const int fr   = lane & 15;
    const int fk   = (lane >> 4) * 8;
    const int sr   = tid >> 2;
    const int sg   = (tid & 3) * 8;

    f32x4 acc[3] = {};

    for (int k0 = 0; k0 < 512; k0 += 32) {
        *reinterpret_cast<half8*>(&Ash[sr][sg]) =
            load_h8<true>(xs, (size_t)(bm + sr) * 512 + k0 + sg);
        if (sr < 48)
            *reinterpret_cast<half8*>(&Bsh[sr][sg]) =
                load_h8<true>(xpw, (size_t)sr * 512 + k0 + sg);
        __syncthreads();
        const half8 af = *reinterpret_cast<const half8*>(&Ash[w * 16 + fr][fk]);
        #pragma unroll
        for (int nf = 0; nf < 3; nf++) {
            const half8 bf = *reinterpret_cast<const half8*>(&Bsh[nf * 16 + fr][fk]);
            acc[nf] = __builtin_amdgcn_mfma_f32_16x16x32_f16(af, bf, acc[nf], 0, 0, 0);
        }
        __syncthreads();
    }

    const int orow = (lane >> 4) * 4;
    const int ocol = lane & 15;
    #pragma unroll
    for (int nf = 0; nf < 3; nf++) {
        #pragma unroll
        for (int r = 0; r < 4; r++) {
            const int gr = bm + w * 16 + orow + r;
            const float v = acc[nf][r];
            if (nf == 0)
                dtr32[(size_t)gr * 16 + ocol] = v;
            else
                xdbl32[(size_t)gr * 32 + (nf - 1) * 16 + ocol] = v;
        }
    }
}

// ---------------------------------------------------------------------------
// (R,C) row-major -> (C,R) row-major transpose + fp32->fp16 (small weights)
// ---------------------------------------------------------------------------
__global__ __launch_bounds__(256)
void cvtT_f2h(const float* __restrict__ in, _Float16* __restrict__ out, int R, int C)
{
    const int g = blockIdx.x * 256 + threadIdx.x;
    if (g < R * C) {
        const int r = g / C, c = g - r * C;
        out[(size_t)c * R + r] = (_Float16)in[g];
    }
}

// ---------------------------------------------------------------------------
// Causal depthwise conv (DC=4 taps) + SiLU.  x lives in xz[:, 0:DI].
// ---------------------------------------------------------------------------
__global__ __launch_bounds__(256)
void conv_silu_k(const float* __restrict__ xz, const float* __restrict__ cw,
                 const float* __restrict__ cb, float* __restrict__ xs)
{
    const int gid = blockIdx.x * 256 + threadIdx.x;
    const int d   = gid & (DI_ - 1);
    const int row = gid >> 9;
    const int t   = row & (L_ - 1);
    float acc = cb[d];
    #pragma unroll
    for (int k = 0; k < DC_; k++) {
        const int tt = t - (DC_ - 1) + k;
        if (tt >= 0)
            acc += xz[(size_t)(row - (DC_ - 1) + k) * (2 * DI_) + d] * cw[d * DC_ + k];
    }
    xs[(size_t)row * DI_ + d] = acc * (1.f / (1.f + __expf(-acc)));
}

// ---------------------------------------------------------------------------
// Scan phase 1: dt inline; per-chunk local recurrence from h=0.
// Block=(chunk c, batch b), thread=channel d. Prefetched xs stream.
// ---------------------------------------------------------------------------
__global__ __launch_bounds__(512)
void scan_phase1(const float* __restrict__ dtr32, const float* __restrict__ dtw,
                 const float* __restrict__ dtb, const float* __restrict__ xs,
                 const float* __restrict__ xdbl32, const float* __restrict__ A_log,
                 float* __restrict__ h_end, float* __restrict__ dtsum)
{
    const int c = blockIdx.x, b = blockIdx.y, d = threadIdx.x;
    __shared__ float Bs[CH][DS_];
    __shared__ float Dtr[CH][DTR_];
    {
        const int tl = threadIdx.x >> 4, n = threadIdx.x & 15;
        if (tl < CH) {
            const size_t row = (size_t)(b * L_ + c * CH + tl);
            Bs[tl][n]  = xdbl32[row * 32 + n];
            Dtr[tl][n] = dtr32[row * 16 + n];
        }
    }
    __syncthreads();
    float Av[DS_], wreg[DTR_];
    #pragma unroll
    for (int n = 0; n < DS_; n++) Av[n] = -expf(A_log[d * DS_ + n]);
    #pragma unroll
    for (int r = 0; r < DTR_; r++) wreg[r] = dtw[d * DTR_ + r];
    const float bd = dtb[d];
    float h[DS_] = {};
    float dts = 0.f;
    const size_t rbase = (size_t)(b * L_ + c * CH) * DI_ + d;
    float xv_n = xs[rbase];
    for (int tl = 0; tl < CH; tl++) {
        const float xv = xv_n;
        if (tl + 1 < CH) xv_n = xs[rbase + (size_t)(tl + 1) * DI_];
        float v = bd;
        #pragma unroll
        for (int r = 0; r < DTR_; r++) v += Dtr[tl][r] * wreg[r];
        const float dtv = (v > 20.f) ? v : log1pf(__expf(v));
        dts += dtv;
        const float dtx = dtv * xv;
        #pragma unroll
        for (int n = 0; n < DS_; n++)
            h[n] = __expf(dtv * Av[n]) * h[n] + dtx * Bs[tl][n];
    }
    const size_t o = (size_t)(b * NCH + c) * DI_ + d;
    f32x4* he = (f32x4*)(h_end + o * DS_);
    #pragma unroll
    for (int q = 0; q < 4; q++) {
        f32x4 v4; v4[0]=h[q*4]; v4[1]=h[q*4+1]; v4[2]=h[q*4+2]; v4[3]=h[q*4+3];
        he[q] = v4;
    }
    dtsum[o] = dts;
}

// ---------------------------------------------------------------------------
// Scan phase 2: sequential combine across chunks (thread=(b,d,n)).
// ---------------------------------------------------------------------------
__global__ __launch_bounds__(256)
void scan_phase2(const float* __restrict__ h_end, const float* __restrict__ dtsum,
                 const float* __restrict__ A_log, float* __restrict__ h_start)
{
    const int gid = blockIdx.x * 256 + threadIdx.x;   // B*DI*DS = 65536
    const int n = gid & 15;
    const int d = (gid >> 4) & (DI_ - 1);
    const int b = gid >> 13;
    const float Av = -expf(A_log[d * DS_ + n]);
    float hs = 0.f;
    for (int c = 0; c < NCH; c++) {
        const size_t o = (size_t)(b * NCH + c) * DI_ + d;
        h_start[o * DS_ + n] = hs;
        hs = __expf(Av * dtsum[o]) * hs + h_end[o * DS_ + n];
    }
}

// ---------------------------------------------------------------------------
// Scan phase 3: replay with incoming h_start, dt inline, emit y fp16.
// Prefetched xs/z streams; vectorized h_start load.
// ---------------------------------------------------------------------------
__global__ __launch_bounds__(512)
void scan_phase3(const float* __restrict__ dtr32, const float* __restrict__ dtw,
                 const float* __restrict__ dtb, const float* __restrict__ xs,
                 const float* __restrict__ xdbl32, const float* __restrict__ A_log,
                 const float* __restrict__ Dv, const float* __restrict__ xz,
                 const float* __restrict__ h_start, _Float16* __restrict__ yout)
{
    const int c = blockIdx.x, b = blockIdx.y, d = threadIdx.x;
    __shared__ float Bs[CH][DS_];
    __shared__ float Cs[CH][DS_];
    __shared__ float Dtr[CH][DTR_];
    {
        const int tl = threadIdx.x >> 4, n = threadIdx.x & 15;
        if (tl < CH) {
            const size_t row = (size_t)(b * L_ + c * CH + tl);
            Bs[tl][n]  = xdbl32[row * 32 + n];
            Cs[tl][n]  = xdbl32[row * 32 + 16 + n];
            Dtr[tl][n] = dtr32[row * 16 + n];
        }
    }
    __syncthreads();
    float Av[DS_], wreg[DTR_];
    #pragma unroll
    for (int n = 0; n < DS_; n++) Av[n] = -expf(A_log[d * DS_ + n]);
    #pragma unroll
    for (int r = 0; r < DTR_; r++) wreg[r] = dtw[d * DTR_ + r];
    const float bd = dtb[d];
    float h[DS_];
    {
        const f32x4* hsv = (const f32x4*)(h_start + ((size_t)(b * NCH + c) * DI_ + d) * DS_);
        #pragma unroll
        for (int q = 0; q < 4; q++) {
            const f32x4 v4 = hsv[q];
            h[q*4]=v4[0]; h[q*4+1]=v4[1]; h[q*4+2]=v4[2]; h[q*4+3]=v4[3];
        }
    }
    const float Dd = Dv[d];
    const int base = b * L_ + c * CH;
    const size_t rbase = (size_t)base * DI_ + d;
    const size_t zbase = (size_t)base * (2 * DI_) + DI_ + d;
    float xv_n = xs[rbase];
    float zv_n = xz[zbase];
    for (int tl = 0; tl < CH; tl++) {
        const float xv = xv_n;
        const float zv = zv_n;
        if (tl + 1 < CH) {
            xv_n = xs[rbase + (size_t)(tl + 1) * DI_];
            zv_n = xz[zbase + (size_t)(tl + 1) * 2 * DI_];
        }
        float v = bd;
        #pragma unroll
        for (int r = 0; r < DTR_; r++) v += Dtr[tl][r] * wreg[r];
        const float dtv = (v > 20.f) ? v : log1pf(__expf(v));
        const float dtx = dtv * xv;
        float acc = 0.f;
        #pragma unroll
        for (int n = 0; n < DS_; n++) {
            h[n] = __expf(dtv * Av[n]) * h[n] + dtx * Bs[tl][n];
            acc += h[n] * Cs[tl][n];
        }
        const float yv = acc + xv * Dd;
        const float g  = zv * (1.f / (1.f + __expf(-zv)));
        yout[rbase + (size_t)tl * DI_] = (_Float16)(yv * g);
    }
}

// ---------------------------------------------------------------------------
// Final N=1 GEMV
// ---------------------------------------------------------------------------
__global__ __launch_bounds__(256)
void final_dot(const float* __restrict__ h2, const float* __restrict__ w3,
               const float* __restrict__ b3, float* __restrict__ out)
{
    __shared__ float w3s[128];
    const int tid = threadIdx.x;
    if (tid < 128) w3s[tid] = w3[tid];
    __syncthreads();
    const int m = blockIdx.x * 256 + tid;
    float acc = b3[0];
    #pragma unroll 4
    for (int k = 0; k < 128; k++) acc += h2[(size_t)m * 128 + k] * w3s[k];
    out[m] = acc;
}

// ---------------------------------------------------------------------------
extern "C" void kernel_launch(void* const* d_in, const int* in_sizes, int n_in,
                              void* d_out, int out_size, void* d_ws, size_t ws_size,
                              hipStream_t stream)
{
    const float* state      = (const float*)d_in[0];
    const float* in_proj_w  = (const float*)d_in[1];
    const float* conv_w     = (const float*)d_in[2];
    const float* conv_b     = (const float*)d_in[3];
    const float* x_proj_w   = (const float*)d_in[4];
    const float* dt_proj_w  = (const float*)d_in[5];
    const float* dt_proj_b  = (const float*)d_in[6];
    const float* A_log      = (const float*)d_in[7];
    const float* Dp         = (const float*)d_in[8];
    const float* out_proj_w = (const float*)d_in[9];
    const float* w1 = (const float*)d_in[10];
    const float* b1 = (const float*)d_in[11];
    const float* w2 = (const float*)d_in[12];
    const float* b2 = (const float*)d_in[13];
    const float* w3 = (const float*)d_in[14];
    const float* b3 = (const float*)d_in[15];

    float* ws      = (float*)d_ws;
    float* xz      = ws;                          // 8,388,608 f (32 MB)
    float* xs      = xz + 8388608;                // 4,194,304 f
    float* xdbl32  = xs + 4194304;                //   262,144 f
    float* dtr32   = xdbl32 + 262144;             //   131,072 f
    float* h_end   = dtr32 + 131072;              // 4,194,304 f (B*NCH*DI*DS)
    float* dtsum   = h_end + 4194304;             //   262,144 f (B*NCH*DI)
    float* h_start = dtsum + 262144;              // 4,194,304 f
    _Float16* w1t  = (_Float16*)(h_start + 4194304); // 65,536 h
    _Float16* w2t  = w1t + 65536;                 //    32,768 h
    // y_h aliases h_end (dead after phase2; phase3 reads only h_start)
    _Float16* y_h  = (_Float16*)h_end;            // 4,194,304 h (8 MB)
    // tail buffers overlay xz (z consumed by phase3 before these are written)
    _Float16* outb_h = (_Float16*)xz;             // 2,097,152 h
    _Float16* h1_h   = (_Float16*)(xz + 1048576); // 2,097,152 h
    float*    h2     = xz + 2097152;              // 1,048,576 f

    // 0. MLP weight transpose+convert (small)
    cvtT_f2h<<<dim3(256), 256, 0, stream>>>(w1, w1t, 256, 256);
    cvtT_f2h<<<dim3(128), 256, 0, stream>>>(w2, w2t, 256, 128);

    // 1. xz = state @ in_proj_w^T   (M=8192, N=1024, K=256), convert-on-stage
    hgemm_k<0, false, false, true, true><<<dim3(M_/128, 1024/128), 256, 0, stream>>>(
        state, DM_, in_proj_w, nullptr, xz, 2*DI_, DM_);
    // 2. causal conv + SiLU -> xs
    conv_silu_k<<<dim3(M_*DI_/256), 256, 0, stream>>>(xz, conv_w, conv_b, xs);
    // 3. x_dbl: MFMA fp16, split outputs (dtr32 / xdbl32)
    xproj_k<<<dim3(M_/64), 256, 0, stream>>>(xs, x_proj_w, dtr32, xdbl32);
    // 4-6. chunked selective scan (dt inline), NCH=64 -> 512 blocks
    scan_phase1<<<dim3(NCH, B_), 512, 0, stream>>>(
        dtr32, dt_proj_w, dt_proj_b, xs, xdbl32, A_log, h_end, dtsum);
    scan_phase2<<<dim3(256), 256, 0, stream>>>(h_end, dtsum, A_log, h_start);
    scan_phase3<<<dim3(NCH, B_), 512, 0, stream>>>(
        dtr32, dt_proj_w, dt_proj_b, xs, xdbl32, A_log, Dp, xz, h_start, y_h);
    // 7. out = y @ out_proj_w^T     (N=256, K=512), W convert-on-stage -> fp16
    hgemm_k<0, false, true, false, true><<<dim3(M_/128, 256/128), 256, 0, stream>>>(
        y_h, DI_, out_proj_w, nullptr, outb_h, DM_, DI_);
    // 8. h1 = relu(out @ w1 + b1)   (N=256, K=256) -> fp16
    hgemm_k<1, true, true, false, false><<<dim3(M_/128, 256/128), 256, 0, stream>>>(
        outb_h, DM_, w1t, b1, h1_h, 256, 256);
    // 9. h2 = relu(h1 @ w2 + b2)    (N=128, K=256) -> fp32
    hgemm_k<1, true, false, false, false><<<dim3(M_/128, 1), 256, 0, stream>>>(
        h1_h, 256, w2t, b2, h2, 128, 256);
    // 10. out = h2 @ w3 + b3        (N=1)
    final_dot<<<dim3(M_/256), 256, 0, stream>>>(h2, w3, b3, (float*)d_out);
}

// Round 7
// 168.752 us; speedup vs baseline: 1.1496x; 1.1020x over previous
//
#include <hip/hip_runtime.h>
#include <cstdint>
#include <cmath>

#define B_   8
#define L_   1024
#define DM_  256
#define DS_  16
#define DC_  4
#define DI_  512
#define DTR_ 16
#define M_   (B_*L_)    // 8192
#define NCH  64         // number of scan chunks
#define CH   16         // chunk length (NCH*CH == L_)

using half8 = __attribute__((ext_vector_type(8))) _Float16;
using f32x4 = __attribute__((ext_vector_type(4))) float;

// ---------------------------------------------------------------------------
// load 8 contiguous elements as fp16, converting from fp32 if F32
// ---------------------------------------------------------------------------
template<bool F32>
__device__ __forceinline__ half8 load_h8(const void* base, size_t off)
{
    if constexpr (F32) {
        const float* p = (const float*)base + off;
        const float4 a = *reinterpret_cast<const float4*>(p);
        const float4 b = *reinterpret_cast<const float4*>(p + 4);
        half8 h;
        h[0] = (_Float16)a.x; h[1] = (_Float16)a.y;
        h[2] = (_Float16)a.z; h[3] = (_Float16)a.w;
        h[4] = (_Float16)b.x; h[5] = (_Float16)b.y;
        h[6] = (_Float16)b.z; h[7] = (_Float16)b.w;
        return h;
    } else {
        return *reinterpret_cast<const half8*>((const _Float16*)base + off);
    }
}

// ---------------------------------------------------------------------------
// fp16 MFMA GEMM: C[m,n] = act(sum_k A[m,k]*W[n,k] + bias[n])
// Tile BM=128, BN=128, BK=32; 256 threads = 4 waves (2x2), wave tile 64x64.
// ---------------------------------------------------------------------------
template<int ACT, bool BIAS, bool OUTH, bool A32, bool W32>
__global__ __launch_bounds__(256)
void hgemm_k(const void* __restrict__ A, int lda,
             const void* __restrict__ W,
             const float* __restrict__ bias,
             void* __restrict__ Cv, int ldc, int K)
{
    __shared__ _Float16 Ash[128][40];
    __shared__ _Float16 Bsh[128][40];
    const int tid  = threadIdx.x;
    const int lane = tid & 63;
    const int w    = tid >> 6;
    const int wm   = (w >> 1) * 64;
    const int wn   = (w & 1) * 64;
    const int bm   = blockIdx.x * 128;
    const int bn   = blockIdx.y * 128;

    const int fr = lane & 15;
    const int fk = (lane >> 4) * 8;
    const int sr = tid >> 2;
    const int sg = (tid & 3) * 8;

    f32x4 acc[4][4] = {};

    for (int k0 = 0; k0 < K; k0 += 32) {
        *reinterpret_cast<half8*>(&Ash[sr][sg]) =
            load_h8<A32>(A, (size_t)(bm + sr) * lda + k0 + sg);
        *reinterpret_cast<half8*>(&Ash[sr + 64][sg]) =
            load_h8<A32>(A, (size_t)(bm + sr + 64) * lda + k0 + sg);
        *reinterpret_cast<half8*>(&Bsh[sr][sg]) =
            load_h8<W32>(W, (size_t)(bn + sr) * K + k0 + sg);
        *reinterpret_cast<half8*>(&Bsh[sr + 64][sg]) =
            load_h8<W32>(W, (size_t)(bn + sr + 64) * K + k0 + sg);
        __syncthreads();

        half8 af[4], bf[4];
        #pragma unroll
        for (int mf = 0; mf < 4; mf++)
            af[mf] = *reinterpret_cast<const half8*>(&Ash[wm + mf * 16 + fr][fk]);
        #pragma unroll
        for (int nf = 0; nf < 4; nf++)
            bf[nf] = *reinterpret_cast<const half8*>(&Bsh[wn + nf * 16 + fr][fk]);
        #pragma unroll
        for (int mf = 0; mf < 4; mf++)
            #pragma unroll
            for (int nf = 0; nf < 4; nf++)
                acc[mf][nf] = __builtin_amdgcn_mfma_f32_16x16x32_f16(
                    af[mf], bf[nf], acc[mf][nf], 0, 0, 0);
        __syncthreads();
    }

    const int orow = (lane >> 4) * 4;
    const int ocol = lane & 15;
    #pragma unroll
    for (int mf = 0; mf < 4; mf++) {
        #pragma unroll
        for (int nf = 0; nf < 4; nf++) {
            const int gc = bn + wn + nf * 16 + ocol;
            float b = BIAS ? bias[gc] : 0.f;
            #pragma unroll
            for (int r = 0; r < 4; r++) {
                const int gr = bm + wm + mf * 16 + orow + r;
                float v = acc[mf][nf][r] + b;
                if (ACT == 1) v = fmaxf(v, 0.f);
                if (OUTH)
                    ((_Float16*)Cv)[(size_t)gr * ldc + gc] = (_Float16)v;
                else
                    ((float*)Cv)[(size_t)gr * ldc + gc] = v;
            }
        }
    }
}

// ---------------------------------------------------------------------------
// x_proj MFMA kernel: xs (M,512) fp32 -> split x_dbl outputs.
// ---------------------------------------------------------------------------
__global__ __launch_bounds__(256)
void xproj_k(const float* __restrict__ xs,
             const float* __restrict__ xpw,
             float* __restrict__ dtr32,
             float* __restrict__ xdbl32)
{
    __shared__ _Float16 Ash[64][40];
    __shared__ _Float16 Bsh[48][40];
    const int tid  = threadIdx.x;
    const int lane = tid & 63;
    const int w    = tid >> 6;
    const int bm   = blockIdx.x * 64;
    const int fr   = lane & 15;
    const int fk   = (lane >> 4) * 8;
    const int sr   = tid >> 2;
    const int sg   = (tid & 3) * 8;

    f32x4 acc[3] = {};

    for (int k0 = 0; k0 < 512; k0 += 32) {
        *reinterpret_cast<half8*>(&Ash[sr][sg]) =
            load_h8<true>(xs, (size_t)(bm + sr) * 512 + k0 + sg);
        if (sr < 48)
            *reinterpret_cast<half8*>(&Bsh[sr][sg]) =
                load_h8<true>(xpw, (size_t)sr * 512 + k0 + sg);
        __syncthreads();
        const half8 af = *reinterpret_cast<const half8*>(&Ash[w * 16 + fr][fk]);
        #pragma unroll
        for (int nf = 0; nf < 3; nf++) {
            const half8 bf = *reinterpret_cast<const half8*>(&Bsh[nf * 16 + fr][fk]);
            acc[nf] = __builtin_amdgcn_mfma_f32_16x16x32_f16(af, bf, acc[nf], 0, 0, 0);
        }
        __syncthreads();
    }

    const int orow = (lane >> 4) * 4;
    const int ocol = lane & 15;
    #pragma unroll
    for (int nf = 0; nf < 3; nf++) {
        #pragma unroll
        for (int r = 0; r < 4; r++) {
            const int gr = bm + w * 16 + orow + r;
            const float v = acc[nf][r];
            if (nf == 0)
                dtr32[(size_t)gr * 16 + ocol] = v;
            else
                xdbl32[(size_t)gr * 32 + (nf - 1) * 16 + ocol] = v;
        }
    }
}

// ---------------------------------------------------------------------------
// (R,C) row-major -> (C,R) row-major transpose + fp32->fp16 (small weights)
// ---------------------------------------------------------------------------
__global__ __launch_bounds__(256)
void cvtT_f2h(const float* __restrict__ in, _Float16* __restrict__ out, int R, int C)
{
    const int g = blockIdx.x * 256 + threadIdx.x;
    if (g < R * C) {
        const int r = g / C, c = g - r * C;
        out[(size_t)c * R + r] = (_Float16)in[g];
    }
}

// ---------------------------------------------------------------------------
// Causal depthwise conv (DC=4 taps) + SiLU.  x lives in xz[:, 0:DI].
// ---------------------------------------------------------------------------
__global__ __launch_bounds__(256)
void conv_silu_k(const float* __restrict__ xz, const float* __restrict__ cw,
                 const float* __restrict__ cb, float* __restrict__ xs)
{
    const int gid = blockIdx.x * 256 + threadIdx.x;
    const int d   = gid & (DI_ - 1);
    const int row = gid >> 9;
    const int t   = row & (L_ - 1);
    float acc = cb[d];
    #pragma unroll
    for (int k = 0; k < DC_; k++) {
        const int tt = t - (DC_ - 1) + k;
        if (tt >= 0)
            acc += xz[(size_t)(row - (DC_ - 1) + k) * (2 * DI_) + d] * cw[d * DC_ + k];
    }
    xs[(size_t)row * DI_ + d] = acc * (1.f / (1.f + __expf(-acc)));
}

// ---------------------------------------------------------------------------
// Scan phase 1: no LDS — B/dtr rows are block-uniform -> s_load path.
// dt inline: softplus(dtr . dtw_row + b) via fast log/exp.
// ---------------------------------------------------------------------------
__global__ __launch_bounds__(512)
void scan_phase1(const float* __restrict__ dtr32, const float* __restrict__ dtw,
                 const float* __restrict__ dtb, const float* __restrict__ xs,
                 const float* __restrict__ xdbl32, const float* __restrict__ A_log,
                 float* __restrict__ h_end, float* __restrict__ dtsum)
{
    const int c = blockIdx.x, b = blockIdx.y, d = threadIdx.x;
    float Av[DS_], wreg[DTR_];
    #pragma unroll
    for (int n = 0; n < DS_; n++) Av[n] = -expf(A_log[d * DS_ + n]);
    #pragma unroll
    for (int r = 0; r < DTR_; r++) wreg[r] = dtw[d * DTR_ + r];
    const float bd = dtb[d];
    float h[DS_] = {};
    float dts = 0.f;
    const int base = b * L_ + c * CH;
    const size_t rbase = (size_t)base * DI_ + d;
    for (int tl = 0; tl < CH; tl++) {
        // block-uniform rows: compiler lowers to s_load (SGPR broadcast)
        const float* dr = dtr32 + (size_t)(base + tl) * 16;
        const float* Br = xdbl32 + (size_t)(base + tl) * 32;
        float v = bd;
        #pragma unroll
        for (int r = 0; r < DTR_; r++) v += dr[r] * wreg[r];
        const float dtv = (v > 20.f) ? v : __logf(1.f + __expf(v));
        const float xv  = xs[rbase + (size_t)tl * DI_];
        dts += dtv;
        const float dtx = dtv * xv;
        #pragma unroll
        for (int n = 0; n < DS_; n++)
            h[n] = __expf(dtv * Av[n]) * h[n] + dtx * Br[n];
    }
    const size_t o = (size_t)(b * NCH + c) * DI_ + d;
    f32x4* he = (f32x4*)(h_end + o * DS_);
    #pragma unroll
    for (int q = 0; q < 4; q++) {
        f32x4 v4; v4[0]=h[q*4]; v4[1]=h[q*4+1]; v4[2]=h[q*4+2]; v4[3]=h[q*4+3];
        he[q] = v4;
    }
    dtsum[o] = dts;
}

// ---------------------------------------------------------------------------
// Scan phase 2: sequential combine across chunks (thread=(b,d,n)).
// Loads are chain-independent -> pipelined by scheduler.
// ---------------------------------------------------------------------------
__global__ __launch_bounds__(256)
void scan_phase2(const float* __restrict__ h_end, const float* __restrict__ dtsum,
                 const float* __restrict__ A_log, float* __restrict__ h_start)
{
    const int gid = blockIdx.x * 256 + threadIdx.x;   // B*DI*DS = 65536
    const int n = gid & 15;
    const int d = (gid >> 4) & (DI_ - 1);
    const int b = gid >> 13;
    const float Av = -expf(A_log[d * DS_ + n]);
    float hs = 0.f;
    for (int c = 0; c < NCH; c++) {
        const size_t o = (size_t)(b * NCH + c) * DI_ + d;
        const float e  = __expf(Av * dtsum[o]);
        const float he = h_end[o * DS_ + n];
        h_start[o * DS_ + n] = hs;
        hs = e * hs + he;
    }
}

// ---------------------------------------------------------------------------
// Scan phase 3: replay with incoming h_start; no LDS (s_load rows);
// dt inline; emit y fp16.
// ---------------------------------------------------------------------------
__global__ __launch_bounds__(512)
void scan_phase3(const float* __restrict__ dtr32, const float* __restrict__ dtw,
                 const float* __restrict__ dtb, const float* __restrict__ xs,
                 const float* __restrict__ xdbl32, const float* __restrict__ A_log,
                 const float* __restrict__ Dv, const float* __restrict__ xz,
                 const float* __restrict__ h_start, _Float16* __restrict__ yout)
{
    const int c = blockIdx.x, b = blockIdx.y, d = threadIdx.x;
    float Av[DS_], wreg[DTR_];
    #pragma unroll
    for (int n = 0; n < DS_; n++) Av[n] = -expf(A_log[d * DS_ + n]);
    #pragma unroll
    for (int r = 0; r < DTR_; r++) wreg[r] = dtw[d * DTR_ + r];
    const float bd = dtb[d];
    float h[DS_];
    {
        const f32x4* hsv = (const f32x4*)(h_start + ((size_t)(b * NCH + c) * DI_ + d) * DS_);
        #pragma unroll
        for (int q = 0; q < 4; q++) {
            const f32x4 v4 = hsv[q];
            h[q*4]=v4[0]; h[q*4+1]=v4[1]; h[q*4+2]=v4[2]; h[q*4+3]=v4[3];
        }
    }
    const float Dd = Dv[d];
    const int base = b * L_ + c * CH;
    const size_t rbase = (size_t)base * DI_ + d;
    const size_t zbase = (size_t)base * (2 * DI_) + DI_ + d;
    for (int tl = 0; tl < CH; tl++) {
        const float* dr = dtr32 + (size_t)(base + tl) * 16;
        const float* Br = xdbl32 + (size_t)(base + tl) * 32;
        float v = bd;
        #pragma unroll
        for (int r = 0; r < DTR_; r++) v += dr[r] * wreg[r];
        const float dtv = (v > 20.f) ? v : __logf(1.f + __expf(v));
        const float xv  = xs[rbase + (size_t)tl * DI_];
        const float zv  = xz[zbase + (size_t)tl * 2 * DI_];
        const float dtx = dtv * xv;
        float acc = 0.f;
        #pragma unroll
        for (int n = 0; n < DS_; n++) {
            h[n] = __expf(dtv * Av[n]) * h[n] + dtx * Br[n];
            acc += h[n] * Br[16 + n];   // C row = second half of xdbl32 row
        }
        const float yv = acc + xv * Dd;
        const float g  = zv * (1.f / (1.f + __expf(-zv)));
        yout[rbase + (size_t)tl * DI_] = (_Float16)(yv * g);
    }
}

// ---------------------------------------------------------------------------
// Final N=1 GEMV
// ---------------------------------------------------------------------------
__global__ __launch_bounds__(256)
void final_dot(const float* __restrict__ h2, const float* __restrict__ w3,
               const float* __restrict__ b3, float* __restrict__ out)
{
    __shared__ float w3s[128];
    const int tid = threadIdx.x;
    if (tid < 128) w3s[tid] = w3[tid];
    __syncthreads();
    const int m = blockIdx.x * 256 + tid;
    float acc = b3[0];
    #pragma unroll 4
    for (int k = 0; k < 128; k++) acc += h2[(size_t)m * 128 + k] * w3s[k];
    out[m] = acc;
}

// ---------------------------------------------------------------------------
extern "C" void kernel_launch(void* const* d_in, const int* in_sizes, int n_in,
                              void* d_out, int out_size, void* d_ws, size_t ws_size,
                              hipStream_t stream)
{
    const float* state      = (const float*)d_in[0];
    const float* in_proj_w  = (const float*)d_in[1];
    const float* conv_w     = (const float*)d_in[2];
    const float* conv_b     = (const float*)d_in[3];
    const float* x_proj_w   = (const float*)d_in[4];
    const float* dt_proj_w  = (const float*)d_in[5];
    const float* dt_proj_b  = (const float*)d_in[6];
    const float* A_log      = (const float*)d_in[7];
    const float* Dp         = (const float*)d_in[8];
    const float* out_proj_w = (const float*)d_in[9];
    const float* w1 = (const float*)d_in[10];
    const float* b1 = (const float*)d_in[11];
    const float* w2 = (const float*)d_in[12];
    const float* b2 = (const float*)d_in[13];
    const float* w3 = (const float*)d_in[14];
    const float* b3 = (const float*)d_in[15];

    float* ws      = (float*)d_ws;
    float* xz      = ws;                          // 8,388,608 f (32 MB)
    float* xs      = xz + 8388608;                // 4,194,304 f
    float* xdbl32  = xs + 4194304;                //   262,144 f
    float* dtr32   = xdbl32 + 262144;             //   131,072 f
    float* h_end   = dtr32 + 131072;              // 4,194,304 f (B*NCH*DI*DS)
    float* dtsum   = h_end + 4194304;             //   262,144 f (B*NCH*DI)
    float* h_start = dtsum + 262144;              // 4,194,304 f
    _Float16* w1t  = (_Float16*)(h_start + 4194304); // 65,536 h
    _Float16* w2t  = w1t + 65536;                 //    32,768 h
    // y_h aliases h_end (dead after phase2; phase3 reads only h_start)
    _Float16* y_h  = (_Float16*)h_end;            // 4,194,304 h (8 MB)
    // tail buffers overlay xz (z consumed by phase3 before these are written)
    _Float16* outb_h = (_Float16*)xz;             // 2,097,152 h
    _Float16* h1_h   = (_Float16*)(xz + 1048576); // 2,097,152 h
    float*    h2     = xz + 2097152;              // 1,048,576 f

    // 0. MLP weight transpose+convert (small)
    cvtT_f2h<<<dim3(256), 256, 0, stream>>>(w1, w1t, 256, 256);
    cvtT_f2h<<<dim3(128), 256, 0, stream>>>(w2, w2t, 256, 128);

    // 1. xz = state @ in_proj_w^T   (M=8192, N=1024, K=256), convert-on-stage
    hgemm_k<0, false, false, true, true><<<dim3(M_/128, 1024/128), 256, 0, stream>>>(
        state, DM_, in_proj_w, nullptr, xz, 2*DI_, DM_);
    // 2. causal conv + SiLU -> xs
    conv_silu_k<<<dim3(M_*DI_/256), 256, 0, stream>>>(xz, conv_w, conv_b, xs);
    // 3. x_dbl: MFMA fp16, split outputs (dtr32 / xdbl32)
    xproj_k<<<dim3(M_/64), 256, 0, stream>>>(xs, x_proj_w, dtr32, xdbl32);
    // 4-6. chunked selective scan (dt inline, no LDS)
    scan_phase1<<<dim3(NCH, B_), 512, 0, stream>>>(
        dtr32, dt_proj_w, dt_proj_b, xs, xdbl32, A_log, h_end, dtsum);
    scan_phase2<<<dim3(256), 256, 0, stream>>>(h_end, dtsum, A_log, h_start);
    scan_phase3<<<dim3(NCH, B_), 512, 0, stream>>>(
        dtr32, dt_proj_w, dt_proj_b, xs, xdbl32, A_log, Dp, xz, h_start, y_h);
    // 7. out = y @ out_proj_w^T     (N=256, K=512), W convert-on-stage -> fp16
    hgemm_k<0, false, true, false, true><<<dim3(M_/128, 256/128), 256, 0, stream>>>(
        y_h, DI_, out_proj_w, nullptr, outb_h, DM_, DI_);
    // 8. h1 = relu(out @ w1 + b1)   (N=256, K=256) -> fp16
    hgemm_k<1, true, true, false, false><<<dim3(M_/128, 256/128), 256, 0, stream>>>(
        outb_h, DM_, w1t, b1, h1_h, 256, 256);
    // 9. h2 = relu(h1 @ w2 + b2)    (N=128, K=256) -> fp32
    hgemm_k<1, true, false, false, false><<<dim3(M_/128, 1), 256, 0, stream>>>(
        h1_h, 256, w2t, b2, h2, 128, 256);
    // 10. out = h2 @ w3 + b3        (N=1)
    final_dot<<<dim3(M_/256), 256, 0, stream>>>(h2, w3, b3, (float*)d_out);
}

// Round 8
// 164.611 us; speedup vs baseline: 1.1785x; 1.0252x over previous
//
#include <hip/hip_runtime.h>
#include <cstdint>
#include <cmath>

#define B_   8
#define L_   1024
#define DM_  256
#define DS_  16
#define DC_  4
#define DI_  512
#define DTR_ 16
#define M_   (B_*L_)    // 8192
#define NCH  64         // number of scan chunks
#define CH   16         // chunk length (NCH*CH == L_)

using half8 = __attribute__((ext_vector_type(8))) _Float16;
using f32x4 = __attribute__((ext_vector_type(4))) float;

// ---------------------------------------------------------------------------
// load 8 contiguous elements as fp16, converting from fp32 if F32
// ---------------------------------------------------------------------------
template<bool F32>
__device__ __forceinline__ half8 load_h8(const void* base, size_t off)
{
    if constexpr (F32) {
        const float* p = (const float*)base + off;
        const float4 a = *reinterpret_cast<const float4*>(p);
        const float4 b = *reinterpret_cast<const float4*>(p + 4);
        half8 h;
        h[0] = (_Float16)a.x; h[1] = (_Float16)a.y;
        h[2] = (_Float16)a.z; h[3] = (_Float16)a.w;
        h[4] = (_Float16)b.x; h[5] = (_Float16)b.y;
        h[6] = (_Float16)b.z; h[7] = (_Float16)b.w;
        return h;
    } else {
        return *reinterpret_cast<const half8*>((const _Float16*)base + off);
    }
}

// ---------------------------------------------------------------------------
// fp16 MFMA GEMM: C[m,n] = act(sum_k A[m,k]*W[n,k] + bias[n])
// Tile BM=128, BN=128, BK=32; 256 threads = 4 waves (2x2), wave tile 64x64.
// ---------------------------------------------------------------------------
template<int ACT, bool BIAS, bool OUTH, bool A32, bool W32>
__global__ __launch_bounds__(256)
void hgemm_k(const void* __restrict__ A, int lda,
             const void* __restrict__ W,
             const float* __restrict__ bias,
             void* __restrict__ Cv, int ldc, int K)
{
    __shared__ _Float16 Ash[128][40];
    __shared__ _Float16 Bsh[128][40];
    const int tid  = threadIdx.x;
    const int lane = tid & 63;
    const int w    = tid >> 6;
    const int wm   = (w >> 1) * 64;
    const int wn   = (w & 1) * 64;
    const int bm   = blockIdx.x * 128;
    const int bn   = blockIdx.y * 128;

    const int fr = lane & 15;
    const int fk = (lane >> 4) * 8;
    const int sr = tid >> 2;
    const int sg = (tid & 3) * 8;

    f32x4 acc[4][4] = {};

    for (int k0 = 0; k0 < K; k0 += 32) {
        *reinterpret_cast<half8*>(&Ash[sr][sg]) =
            load_h8<A32>(A, (size_t)(bm + sr) * lda + k0 + sg);
        *reinterpret_cast<half8*>(&Ash[sr + 64][sg]) =
            load_h8<A32>(A, (size_t)(bm + sr + 64) * lda + k0 + sg);
        *reinterpret_cast<half8*>(&Bsh[sr][sg]) =
            load_h8<W32>(W, (size_t)(bn + sr) * K + k0 + sg);
        *reinterpret_cast<half8*>(&Bsh[sr + 64][sg]) =
            load_h8<W32>(W, (size_t)(bn + sr + 64) * K + k0 + sg);
        __syncthreads();

        half8 af[4], bf[4];
        #pragma unroll
        for (int mf = 0; mf < 4; mf++)
            af[mf] = *reinterpret_cast<const half8*>(&Ash[wm + mf * 16 + fr][fk]);
        #pragma unroll
        for (int nf = 0; nf < 4; nf++)
            bf[nf] = *reinterpret_cast<const half8*>(&Bsh[wn + nf * 16 + fr][fk]);
        #pragma unroll
        for (int mf = 0; mf < 4; mf++)
            #pragma unroll
            for (int nf = 0; nf < 4; nf++)
                acc[mf][nf] = __builtin_amdgcn_mfma_f32_16x16x32_f16(
                    af[mf], bf[nf], acc[mf][nf], 0, 0, 0);
        __syncthreads();
    }

    const int orow = (lane >> 4) * 4;
    const int ocol = lane & 15;
    #pragma unroll
    for (int mf = 0; mf < 4; mf++) {
        #pragma unroll
        for (int nf = 0; nf < 4; nf++) {
            const int gc = bn + wn + nf * 16 + ocol;
            float b = BIAS ? bias[gc] : 0.f;
            #pragma unroll
            for (int r = 0; r < 4; r++) {
                const int gr = bm + wm + mf * 16 + orow + r;
                float v = acc[mf][nf][r] + b;
                if (ACT == 1) v = fmaxf(v, 0.f);
                if (OUTH)
                    ((_Float16*)Cv)[(size_t)gr * ldc + gc] = (_Float16)v;
                else
                    ((float*)Cv)[(size_t)gr * ldc + gc] = v;
            }
        }
    }
}

// ---------------------------------------------------------------------------
// x_proj MFMA kernel: xs (M,512) fp32 -> split x_dbl outputs.
// ---------------------------------------------------------------------------
__global__ __launch_bounds__(256)
void xproj_k(const float* __restrict__ xs,
             const float* __restrict__ xpw,
             float* __restrict__ dtr32,
             float* __restrict__ xdbl32)
{
    __shared__ _Float16 Ash[64][40];
    __shared__ _Float16 Bsh[48][40];
    const int tid  = threadIdx.x;
    const int lane = tid & 63;
    const int w    = tid >> 6;
    const int bm   = blockIdx.x * 64;
    const int fr   = lane & 15;
    const int fk   = (lane >> 4) * 8;
    const int sr   = tid >> 2;
    const int sg   = (tid & 3) * 8;

    f32x4 acc[3] = {};

    for (int k0 = 0; k0 < 512; k0 += 32) {
        *reinterpret_cast<half8*>(&Ash[sr][sg]) =
            load_h8<true>(xs, (size_t)(bm + sr) * 512 + k0 + sg);
        if (sr < 48)
            *reinterpret_cast<half8*>(&Bsh[sr][sg]) =
                load_h8<true>(xpw, (size_t)sr * 512 + k0 + sg);
        __syncthreads();
        const half8 af = *reinterpret_cast<const half8*>(&Ash[w * 16 + fr][fk]);
        #pragma unroll
        for (int nf = 0; nf < 3; nf++) {
            const half8 bf = *reinterpret_cast<const half8*>(&Bsh[nf * 16 + fr][fk]);
            acc[nf] = __builtin_amdgcn_mfma_f32_16x16x32_f16(af, bf, acc[nf], 0, 0, 0);
        }
        __syncthreads();
    }

    const int orow = (lane >> 4) * 4;
    const int ocol = lane & 15;
    #pragma unroll
    for (int nf = 0; nf < 3; nf++) {
        #pragma unroll
        for (int r = 0; r < 4; r++) {
            const int gr = bm + w * 16 + orow + r;
            const float v = acc[nf][r];
            if (nf == 0)
                dtr32[(size_t)gr * 16 + ocol] = v;
            else
                xdbl32[(size_t)gr * 32 + (nf - 1) * 16 + ocol] = v;
        }
    }
}

// ---------------------------------------------------------------------------
// (R,C) row-major -> (C,R) row-major transpose + fp32->fp16 (small weights)
// ---------------------------------------------------------------------------
__global__ __launch_bounds__(256)
void cvtT_f2h(const float* __restrict__ in, _Float16* __restrict__ out, int R, int C)
{
    const int g = blockIdx.x * 256 + threadIdx.x;
    if (g < R * C) {
        const int r = g / C, c = g - r * C;
        out[(size_t)c * R + r] = (_Float16)in[g];
    }
}

// ---------------------------------------------------------------------------
// dt precompute: dt[t,d] = softplus(dtr[t,:] . dtw[d,:] + dtb[d]) -> fp16.
// Block = 4 rows (t), 512 threads (d). dtr rows are block-uniform (s_load).
// ---------------------------------------------------------------------------
__global__ __launch_bounds__(512)
void dt_k(const float* __restrict__ dtr32, const float* __restrict__ dtw,
          const float* __restrict__ dtb, _Float16* __restrict__ dth)
{
    const int d = threadIdx.x;
    const int t0 = blockIdx.x * 4;
    float wreg[DTR_];
    #pragma unroll
    for (int r = 0; r < DTR_; r++) wreg[r] = dtw[d * DTR_ + r];
    const float bd = dtb[d];
    #pragma unroll
    for (int i = 0; i < 4; i++) {
        const float* dr = dtr32 + (size_t)(t0 + i) * 16;   // block-uniform
        float v = bd;
        #pragma unroll
        for (int r = 0; r < DTR_; r++) v += dr[r] * wreg[r];
        const float dtv = (v > 20.f) ? v : __logf(1.f + __expf(v));
        dth[(size_t)(t0 + i) * DI_ + d] = (_Float16)dtv;
    }
}

// ---------------------------------------------------------------------------
// Causal depthwise conv (DC=4 taps) + SiLU, float4-vectorized (4 channels/thr).
// ---------------------------------------------------------------------------
__global__ __launch_bounds__(256)
void conv_silu_k(const float* __restrict__ xz, const float* __restrict__ cw,
                 const float* __restrict__ cb, float* __restrict__ xs)
{
    const int gid = blockIdx.x * 256 + threadIdx.x;   // 0 .. M_*DI_/4-1
    const int d4  = (gid & 127) << 2;                 // 0,4,..,508
    const int row = gid >> 7;
    const int t   = row & (L_ - 1);
    float4 acc = *reinterpret_cast<const float4*>(cb + d4);
    float4 cwv[4];
    #pragma unroll
    for (int i = 0; i < 4; i++)
        cwv[i] = *reinterpret_cast<const float4*>(cw + (d4 + i) * DC_);
    #pragma unroll
    for (int k = 0; k < DC_; k++) {
        const int tt = t - (DC_ - 1) + k;
        if (tt >= 0) {
            const float4 xv = *reinterpret_cast<const float4*>(
                xz + (size_t)(row - (DC_ - 1) + k) * (2 * DI_) + d4);
            acc.x += xv.x * ((const float*)&cwv[0])[k];
            acc.y += xv.y * ((const float*)&cwv[1])[k];
            acc.z += xv.z * ((const float*)&cwv[2])[k];
            acc.w += xv.w * ((const float*)&cwv[3])[k];
        }
    }
    float4 o;
    o.x = acc.x * (1.f / (1.f + __expf(-acc.x)));
    o.y = acc.y * (1.f / (1.f + __expf(-acc.y)));
    o.z = acc.z * (1.f / (1.f + __expf(-acc.z)));
    o.w = acc.w * (1.f / (1.f + __expf(-acc.w)));
    *reinterpret_cast<float4*>(xs + (size_t)row * DI_ + d4) = o;
}

// ---------------------------------------------------------------------------
// Scan phase 1: dt from precomputed fp16; B rows block-uniform (s_load).
// ---------------------------------------------------------------------------
__global__ __launch_bounds__(512)
void scan_phase1(const _Float16* __restrict__ dth, const float* __restrict__ xs,
                 const float* __restrict__ xdbl32, const float* __restrict__ A_log,
                 float* __restrict__ h_end, float* __restrict__ dtsum)
{
    const int c = blockIdx.x, b = blockIdx.y, d = threadIdx.x;
    float Av[DS_];
    #pragma unroll
    for (int n = 0; n < DS_; n++) Av[n] = -expf(A_log[d * DS_ + n]);
    float h[DS_] = {};
    float dts = 0.f;
    const int base = b * L_ + c * CH;
    const size_t rbase = (size_t)base * DI_ + d;
    for (int tl = 0; tl < CH; tl++) {
        const float* Br = xdbl32 + (size_t)(base + tl) * 32;   // s_load
        const float dtv = (float)dth[rbase + (size_t)tl * DI_];
        const float xv  = xs[rbase + (size_t)tl * DI_];
        dts += dtv;
        const float dtx = dtv * xv;
        #pragma unroll
        for (int n = 0; n < DS_; n++)
            h[n] = __expf(dtv * Av[n]) * h[n] + dtx * Br[n];
    }
    const size_t o = (size_t)(b * NCH + c) * DI_ + d;
    f32x4* he = (f32x4*)(h_end + o * DS_);
    #pragma unroll
    for (int q = 0; q < 4; q++) {
        f32x4 v4; v4[0]=h[q*4]; v4[1]=h[q*4+1]; v4[2]=h[q*4+2]; v4[3]=h[q*4+3];
        he[q] = v4;
    }
    dtsum[o] = dts;
}

// ---------------------------------------------------------------------------
// Scan phase 2: sequential combine across chunks (thread=(b,d,n)).
// ---------------------------------------------------------------------------
__global__ __launch_bounds__(256)
void scan_phase2(const float* __restrict__ h_end, const float* __restrict__ dtsum,
                 const float* __restrict__ A_log, float* __restrict__ h_start)
{
    const int gid = blockIdx.x * 256 + threadIdx.x;   // B*DI*DS = 65536
    const int n = gid & 15;
    const int d = (gid >> 4) & (DI_ - 1);
    const int b = gid >> 13;
    const float Av = -expf(A_log[d * DS_ + n]);
    float hs = 0.f;
    for (int c = 0; c < NCH; c++) {
        const size_t o = (size_t)(b * NCH + c) * DI_ + d;
        const float e  = __expf(Av * dtsum[o]);
        const float he = h_end[o * DS_ + n];
        h_start[o * DS_ + n] = hs;
        hs = e * hs + he;
    }
}

// ---------------------------------------------------------------------------
// Scan phase 3: replay with incoming h_start; dt precomputed; emit y fp16.
// ---------------------------------------------------------------------------
__global__ __launch_bounds__(512)
void scan_phase3(const _Float16* __restrict__ dth, const float* __restrict__ xs,
                 const float* __restrict__ xdbl32, const float* __restrict__ A_log,
                 const float* __restrict__ Dv, const float* __restrict__ xz,
                 const float* __restrict__ h_start, _Float16* __restrict__ yout)
{
    const int c = blockIdx.x, b = blockIdx.y, d = threadIdx.x;
    float Av[DS_];
    #pragma unroll
    for (int n = 0; n < DS_; n++) Av[n] = -expf(A_log[d * DS_ + n]);
    float h[DS_];
    {
        const f32x4* hsv = (const f32x4*)(h_start + ((size_t)(b * NCH + c) * DI_ + d) * DS_);
        #pragma unroll
        for (int q = 0; q < 4; q++) {
            const f32x4 v4 = hsv[q];
            h[q*4]=v4[0]; h[q*4+1]=v4[1]; h[q*4+2]=v4[2]; h[q*4+3]=v4[3];
        }
    }
    const float Dd = Dv[d];
    const int base = b * L_ + c * CH;
    const size_t rbase = (size_t)base * DI_ + d;
    const size_t zbase = (size_t)base * (2 * DI_) + DI_ + d;
    for (int tl = 0; tl < CH; tl++) {
        const float* Br = xdbl32 + (size_t)(base + tl) * 32;   // s_load
        const float dtv = (float)dth[rbase + (size_t)tl * DI_];
        const float xv  = xs[rbase + (size_t)tl * DI_];
        const float zv  = xz[zbase + (size_t)tl * 2 * DI_];
        const float dtx = dtv * xv;
        float acc = 0.f;
        #pragma unroll
        for (int n = 0; n < DS_; n++) {
            h[n] = __expf(dtv * Av[n]) * h[n] + dtx * Br[n];
            acc += h[n] * Br[16 + n];   // C row = second half of xdbl32 row
        }
        const float yv = acc + xv * Dd;
        const float g  = zv * (1.f / (1.f + __expf(-zv)));
        yout[rbase + (size_t)tl * DI_] = (_Float16)(yv * g);
    }
}

// ---------------------------------------------------------------------------
// Final N=1 GEMV
// ---------------------------------------------------------------------------
__global__ __launch_bounds__(256)
void final_dot(const float* __restrict__ h2, const float* __restrict__ w3,
               const float* __restrict__ b3, float* __restrict__ out)
{
    __shared__ float w3s[128];
    const int tid = threadIdx.x;
    if (tid < 128) w3s[tid] = w3[tid];
    __syncthreads();
    const int m = blockIdx.x * 256 + tid;
    float acc = b3[0];
    #pragma unroll 4
    for (int k = 0; k < 128; k++) acc += h2[(size_t)m * 128 + k] * w3s[k];
    out[m] = acc;
}

// ---------------------------------------------------------------------------
extern "C" void kernel_launch(void* const* d_in, const int* in_sizes, int n_in,
                              void* d_out, int out_size, void* d_ws, size_t ws_size,
                              hipStream_t stream)
{
    const float* state      = (const float*)d_in[0];
    const float* in_proj_w  = (const float*)d_in[1];
    const float* conv_w     = (const float*)d_in[2];
    const float* conv_b     = (const float*)d_in[3];
    const float* x_proj_w   = (const float*)d_in[4];
    const float* dt_proj_w  = (const float*)d_in[5];
    const float* dt_proj_b  = (const float*)d_in[6];
    const float* A_log      = (const float*)d_in[7];
    const float* Dp         = (const float*)d_in[8];
    const float* out_proj_w = (const float*)d_in[9];
    const float* w1 = (const float*)d_in[10];
    const float* b1 = (const float*)d_in[11];
    const float* w2 = (const float*)d_in[12];
    const float* b2 = (const float*)d_in[13];
    const float* w3 = (const float*)d_in[14];
    const float* b3 = (const float*)d_in[15];

    float* ws      = (float*)d_ws;
    float* xz      = ws;                          // 8,388,608 f (32 MB)
    float* xs      = xz + 8388608;                // 4,194,304 f
    float* xdbl32  = xs + 4194304;                //   262,144 f
    float* dtr32   = xdbl32 + 262144;             //   131,072 f
    float* h_end   = dtr32 + 131072;              // 4,194,304 f (B*NCH*DI*DS)
    float* dtsum   = h_end + 4194304;             //   262,144 f (B*NCH*DI)
    float* h_start = dtsum + 262144;              // 4,194,304 f
    _Float16* w1t  = (_Float16*)(h_start + 4194304); // 65,536 h
    _Float16* w2t  = w1t + 65536;                 //    32,768 h
    _Float16* dth  = w2t + 32768;                 // 4,194,304 h (8 MB: M_*DI_)
    // y_h aliases h_end (dead after phase2; phase3 reads only h_start)
    _Float16* y_h  = (_Float16*)h_end;            // 4,194,304 h (8 MB)
    // tail buffers overlay xz (z consumed by phase3 before these are written)
    _Float16* outb_h = (_Float16*)xz;             // 2,097,152 h
    _Float16* h1_h   = (_Float16*)(xz + 1048576); // 2,097,152 h
    float*    h2     = xz + 2097152;              // 1,048,576 f

    // 0. MLP weight transpose+convert (small)
    cvtT_f2h<<<dim3(256), 256, 0, stream>>>(w1, w1t, 256, 256);
    cvtT_f2h<<<dim3(128), 256, 0, stream>>>(w2, w2t, 256, 128);

    // 1. xz = state @ in_proj_w^T   (M=8192, N=1024, K=256), convert-on-stage
    hgemm_k<0, false, false, true, true><<<dim3(M_/128, 1024/128), 256, 0, stream>>>(
        state, DM_, in_proj_w, nullptr, xz, 2*DI_, DM_);
    // 2. causal conv + SiLU -> xs (float4)
    conv_silu_k<<<dim3(M_*DI_/4/256), 256, 0, stream>>>(xz, conv_w, conv_b, xs);
    // 3. x_dbl: MFMA fp16, split outputs (dtr32 / xdbl32)
    xproj_k<<<dim3(M_/64), 256, 0, stream>>>(xs, x_proj_w, dtr32, xdbl32);
    // 4. dt = softplus(dtr @ dtw^T + b) -> fp16 (throughput kernel)
    dt_k<<<dim3(M_/4), 512, 0, stream>>>(dtr32, dt_proj_w, dt_proj_b, dth);
    // 5-7. chunked selective scan (precomputed dt, no LDS)
    scan_phase1<<<dim3(NCH, B_), 512, 0, stream>>>(
        dth, xs, xdbl32, A_log, h_end, dtsum);
    scan_phase2<<<dim3(256), 256, 0, stream>>>(h_end, dtsum, A_log, h_start);
    scan_phase3<<<dim3(NCH, B_), 512, 0, stream>>>(
        dth, xs, xdbl32, A_log, Dp, xz, h_start, y_h);
    // 8. out = y @ out_proj_w^T     (N=256, K=512), W convert-on-stage -> fp16
    hgemm_k<0, false, true, false, true><<<dim3(M_/128, 256/128), 256, 0, stream>>>(
        y_h, DI_, out_proj_w, nullptr, outb_h, DM_, DI_);
    // 9. h1 = relu(out @ w1 + b1)   (N=256, K=256) -> fp16
    hgemm_k<1, true, true, false, false><<<dim3(M_/128, 256/128), 256, 0, stream>>>(
        outb_h, DM_, w1t, b1, h1_h, 256, 256);
    // 10. h2 = relu(h1 @ w2 + b2)   (N=128, K=256) -> fp32
    hgemm_k<1, true, false, false, false><<<dim3(M_/128, 1), 256, 0, stream>>>(
        h1_h, 256, w2t, b2, h2, 128, 256);
    // 11. out = h2 @ w3 + b3        (N=1)
    final_dot<<<dim3(M_/256), 256, 0, stream>>>(h2, w3, b3, (float*)d_out);
}

// Round 9
// 142.360 us; speedup vs baseline: 1.3628x; 1.1563x over previous
//
#include <hip/hip_runtime.h>
#include <cstdint>
#include <cmath>

#define B_   8
#define L_   1024
#define DM_  256
#define DS_  16
#define DC_  4
#define DI_  512
#define DTR_ 16
#define M_   (B_*L_)    // 8192
#define NCH  64         // number of scan chunks
#define CH   16         // chunk length (NCH*CH == L_)

using half8 = __attribute__((ext_vector_type(8))) _Float16;
using half4 = __attribute__((ext_vector_type(4))) _Float16;
using f32x4 = __attribute__((ext_vector_type(4))) float;

// ---------------------------------------------------------------------------
// load 8 contiguous elements as fp16, converting from fp32 if F32
// ---------------------------------------------------------------------------
template<bool F32>
__device__ __forceinline__ half8 load_h8(const void* base, size_t off)
{
    if constexpr (F32) {
        const float* p = (const float*)base + off;
        const float4 a = *reinterpret_cast<const float4*>(p);
        const float4 b = *reinterpret_cast<const float4*>(p + 4);
        half8 h;
        h[0] = (_Float16)a.x; h[1] = (_Float16)a.y;
        h[2] = (_Float16)a.z; h[3] = (_Float16)a.w;
        h[4] = (_Float16)b.x; h[5] = (_Float16)b.y;
        h[6] = (_Float16)b.z; h[7] = (_Float16)b.w;
        return h;
    } else {
        return *reinterpret_cast<const half8*>((const _Float16*)base + off);
    }
}

// ---------------------------------------------------------------------------
// fp16 MFMA GEMM, tile 128x128 (in_proj).  OMODE: 0=f32 out, 2=splitz
// (cols<512 -> fp32 xbuf; cols>=512 -> silu applied, fp16 gbuf; ldc=512 each)
// ---------------------------------------------------------------------------
template<int OMODE, bool A32, bool W32>
__global__ __launch_bounds__(256)
void hgemm_k(const void* __restrict__ A, int lda,
             const void* __restrict__ W,
             void* __restrict__ Cv, void* __restrict__ Cv2, int ldc, int K)
{
    __shared__ _Float16 Ash[128][40];
    __shared__ _Float16 Bsh[128][40];
    const int tid  = threadIdx.x;
    const int lane = tid & 63;
    const int w    = tid >> 6;
    const int wm   = (w >> 1) * 64;
    const int wn   = (w & 1) * 64;
    const int bm   = blockIdx.x * 128;
    const int bn   = blockIdx.y * 128;

    const int fr = lane & 15;
    const int fk = (lane >> 4) * 8;
    const int sr = tid >> 2;
    const int sg = (tid & 3) * 8;

    f32x4 acc[4][4] = {};

    for (int k0 = 0; k0 < K; k0 += 32) {
        *reinterpret_cast<half8*>(&Ash[sr][sg]) =
            load_h8<A32>(A, (size_t)(bm + sr) * lda + k0 + sg);
        *reinterpret_cast<half8*>(&Ash[sr + 64][sg]) =
            load_h8<A32>(A, (size_t)(bm + sr + 64) * lda + k0 + sg);
        *reinterpret_cast<half8*>(&Bsh[sr][sg]) =
            load_h8<W32>(W, (size_t)(bn + sr) * K + k0 + sg);
        *reinterpret_cast<half8*>(&Bsh[sr + 64][sg]) =
            load_h8<W32>(W, (size_t)(bn + sr + 64) * K + k0 + sg);
        __syncthreads();

        half8 af[4], bf[4];
        #pragma unroll
        for (int mf = 0; mf < 4; mf++)
            af[mf] = *reinterpret_cast<const half8*>(&Ash[wm + mf * 16 + fr][fk]);
        #pragma unroll
        for (int nf = 0; nf < 4; nf++)
            bf[nf] = *reinterpret_cast<const half8*>(&Bsh[wn + nf * 16 + fr][fk]);
        #pragma unroll
        for (int mf = 0; mf < 4; mf++)
            #pragma unroll
            for (int nf = 0; nf < 4; nf++)
                acc[mf][nf] = __builtin_amdgcn_mfma_f32_16x16x32_f16(
                    af[mf], bf[nf], acc[mf][nf], 0, 0, 0);
        __syncthreads();
    }

    const int orow = (lane >> 4) * 4;
    const int ocol = lane & 15;
    const bool zside = (OMODE == 2) && (bn >= DI_);
    #pragma unroll
    for (int mf = 0; mf < 4; mf++) {
        #pragma unroll
        for (int nf = 0; nf < 4; nf++) {
            const int gc = bn + wn + nf * 16 + ocol;
            #pragma unroll
            for (int r = 0; r < 4; r++) {
                const int gr = bm + wm + mf * 16 + orow + r;
                const float v = acc[mf][nf][r];
                if (OMODE == 2) {
                    if (zside) {
                        const float g = v * (1.f / (1.f + __expf(-v)));
                        ((_Float16*)Cv2)[(size_t)gr * DI_ + (gc - DI_)] = (_Float16)g;
                    } else {
                        ((float*)Cv)[(size_t)gr * DI_ + gc] = v;
                    }
                } else {
                    ((float*)Cv)[(size_t)gr * ldc + gc] = v;
                }
            }
        }
    }
}

// ---------------------------------------------------------------------------
// fp16 MFMA GEMM, tile 64x64 (tail GEMMs: out_proj, mlp1, mlp2).
// 4 waves, each a 32x32 quadrant (2x2 fragments). ACT: 0 none, 1 relu.
// ---------------------------------------------------------------------------
template<int ACT, bool BIAS, bool OUTH, bool W32>
__global__ __launch_bounds__(256)
void hgemm64_k(const _Float16* __restrict__ A, int lda,
               const void* __restrict__ W,
               const float* __restrict__ bias,
               void* __restrict__ Cv, int ldc, int K)
{
    __shared__ _Float16 Ash[64][40];
    __shared__ _Float16 Bsh[64][40];
    const int tid  = threadIdx.x;
    const int lane = tid & 63;
    const int w    = tid >> 6;
    const int wm   = (w >> 1) * 32;
    const int wn   = (w & 1) * 32;
    const int bm   = blockIdx.x * 64;
    const int bn   = blockIdx.y * 64;

    const int fr = lane & 15;
    const int fk = (lane >> 4) * 8;
    const int sr = tid >> 2;
    const int sg = (tid & 3) * 8;

    f32x4 acc[2][2] = {};

    for (int k0 = 0; k0 < K; k0 += 32) {
        *reinterpret_cast<half8*>(&Ash[sr][sg]) =
            load_h8<false>(A, (size_t)(bm + sr) * lda + k0 + sg);
        *reinterpret_cast<half8*>(&Bsh[sr][sg]) =
            load_h8<W32>(W, (size_t)(bn + sr) * K + k0 + sg);
        __syncthreads();

        half8 af[2], bf[2];
        #pragma unroll
        for (int mf = 0; mf < 2; mf++)
            af[mf] = *reinterpret_cast<const half8*>(&Ash[wm + mf * 16 + fr][fk]);
        #pragma unroll
        for (int nf = 0; nf < 2; nf++)
            bf[nf] = *reinterpret_cast<const half8*>(&Bsh[wn + nf * 16 + fr][fk]);
        #pragma unroll
        for (int mf = 0; mf < 2; mf++)
            #pragma unroll
            for (int nf = 0; nf < 2; nf++)
                acc[mf][nf] = __builtin_amdgcn_mfma_f32_16x16x32_f16(
                    af[mf], bf[nf], acc[mf][nf], 0, 0, 0);
        __syncthreads();
    }

    const int orow = (lane >> 4) * 4;
    const int ocol = lane & 15;
    #pragma unroll
    for (int mf = 0; mf < 2; mf++) {
        #pragma unroll
        for (int nf = 0; nf < 2; nf++) {
            const int gc = bn + wn + nf * 16 + ocol;
            float b = BIAS ? bias[gc] : 0.f;
            #pragma unroll
            for (int r = 0; r < 4; r++) {
                const int gr = bm + wm + mf * 16 + orow + r;
                float v = acc[mf][nf][r] + b;
                if (ACT == 1) v = fmaxf(v, 0.f);
                if (OUTH)
                    ((_Float16*)Cv)[(size_t)gr * ldc + gc] = (_Float16)v;
                else
                    ((float*)Cv)[(size_t)gr * ldc + gc] = v;
            }
        }
    }
}

// ---------------------------------------------------------------------------
// x_proj MFMA kernel: xs (M,512) fp16 -> split x_dbl outputs (fp32).
// ---------------------------------------------------------------------------
__global__ __launch_bounds__(256)
void xproj_k(const _Float16* __restrict__ xs,
             const float* __restrict__ xpw,
             float* __restrict__ dtr32,
             float* __restrict__ xdbl32)
{
    __shared__ _Float16 Ash[64][40];
    __shared__ _Float16 Bsh[48][40];
    const int tid  = threadIdx.x;
    const int lane = tid & 63;
    const int w    = tid >> 6;
    const int bm   = blockIdx.x * 64;
    const int fr   = lane & 15;
    const int fk   = (lane >> 4) * 8;
    const int sr   = tid >> 2;
    const int sg   = (tid & 3) * 8;

    f32x4 acc[3] = {};

    for (int k0 = 0; k0 < 512; k0 += 32) {
        *reinterpret_cast<half8*>(&Ash[sr][sg]) =
            load_h8<false>(xs, (size_t)(bm + sr) * 512 + k0 + sg);
        if (sr < 48)
            *reinterpret_cast<half8*>(&Bsh[sr][sg]) =
                load_h8<true>(xpw, (size_t)sr * 512 + k0 + sg);
        __syncthreads();
        const half8 af = *reinterpret_cast<const half8*>(&Ash[w * 16 + fr][fk]);
        #pragma unroll
        for (int nf = 0; nf < 3; nf++) {
            const half8 bf = *reinterpret_cast<const half8*>(&Bsh[nf * 16 + fr][fk]);
            acc[nf] = __builtin_amdgcn_mfma_f32_16x16x32_f16(af, bf, acc[nf], 0, 0, 0);
        }
        __syncthreads();
    }

    const int orow = (lane >> 4) * 4;
    const int ocol = lane & 15;
    #pragma unroll
    for (int nf = 0; nf < 3; nf++) {
        #pragma unroll
        for (int r = 0; r < 4; r++) {
            const int gr = bm + w * 16 + orow + r;
            const float v = acc[nf][r];
            if (nf == 0)
                dtr32[(size_t)gr * 16 + ocol] = v;
            else
                xdbl32[(size_t)gr * 32 + (nf - 1) * 16 + ocol] = v;
        }
    }
}

// ---------------------------------------------------------------------------
// (R,C) row-major -> (C,R) row-major transpose + fp32->fp16 (small weights)
// ---------------------------------------------------------------------------
__global__ __launch_bounds__(256)
void cvtT_f2h(const float* __restrict__ in, _Float16* __restrict__ out, int R, int C)
{
    const int g = blockIdx.x * 256 + threadIdx.x;
    if (g < R * C) {
        const int r = g / C, c = g - r * C;
        out[(size_t)c * R + r] = (_Float16)in[g];
    }
}

// ---------------------------------------------------------------------------
// dt precompute: dt[t,d] = softplus(dtr[t,:] . dtw[d,:] + dtb[d]) -> fp16.
// ---------------------------------------------------------------------------
__global__ __launch_bounds__(512)
void dt_k(const float* __restrict__ dtr32, const float* __restrict__ dtw,
          const float* __restrict__ dtb, _Float16* __restrict__ dth)
{
    const int d = threadIdx.x;
    const int t0 = blockIdx.x * 4;
    float wreg[DTR_];
    #pragma unroll
    for (int r = 0; r < DTR_; r++) wreg[r] = dtw[d * DTR_ + r];
    const float bd = dtb[d];
    #pragma unroll
    for (int i = 0; i < 4; i++) {
        const float* dr = dtr32 + (size_t)(t0 + i) * 16;   // block-uniform
        float v = bd;
        #pragma unroll
        for (int r = 0; r < DTR_; r++) v += dr[r] * wreg[r];
        const float dtv = (v > 20.f) ? v : __logf(1.f + __expf(v));
        dth[(size_t)(t0 + i) * DI_ + d] = (_Float16)dtv;
    }
}

// ---------------------------------------------------------------------------
// Causal depthwise conv (DC=4 taps) + SiLU; fp32 in (compact), fp16 out.
// ---------------------------------------------------------------------------
__global__ __launch_bounds__(256)
void conv_silu_k(const float* __restrict__ xbuf, const float* __restrict__ cw,
                 const float* __restrict__ cb, _Float16* __restrict__ xs)
{
    const int gid = blockIdx.x * 256 + threadIdx.x;   // 0 .. M_*DI_/4-1
    const int d4  = (gid & 127) << 2;                 // 0,4,..,508
    const int row = gid >> 7;
    const int t   = row & (L_ - 1);
    float4 acc = *reinterpret_cast<const float4*>(cb + d4);
    float4 cwv[4];
    #pragma unroll
    for (int i = 0; i < 4; i++)
        cwv[i] = *reinterpret_cast<const float4*>(cw + (d4 + i) * DC_);
    #pragma unroll
    for (int k = 0; k < DC_; k++) {
        const int tt = t - (DC_ - 1) + k;
        if (tt >= 0) {
            const float4 xv = *reinterpret_cast<const float4*>(
                xbuf + (size_t)(row - (DC_ - 1) + k) * DI_ + d4);
            acc.x += xv.x * ((const float*)&cwv[0])[k];
            acc.y += xv.y * ((const float*)&cwv[1])[k];
            acc.z += xv.z * ((const float*)&cwv[2])[k];
            acc.w += xv.w * ((const float*)&cwv[3])[k];
        }
    }
    half4 o;
    o[0] = (_Float16)(acc.x * (1.f / (1.f + __expf(-acc.x))));
    o[1] = (_Float16)(acc.y * (1.f / (1.f + __expf(-acc.y))));
    o[2] = (_Float16)(acc.z * (1.f / (1.f + __expf(-acc.z))));
    o[3] = (_Float16)(acc.w * (1.f / (1.f + __expf(-acc.w))));
    *reinterpret_cast<half4*>(xs + (size_t)row * DI_ + d4) = o;
}

// ---------------------------------------------------------------------------
// Scan phase 1: fp16 dt/xs in, fp16 h_end out; B rows block-uniform (s_load).
// ---------------------------------------------------------------------------
__global__ __launch_bounds__(512)
void scan_phase1(const _Float16* __restrict__ dth, const _Float16* __restrict__ xs,
                 const float* __restrict__ xdbl32, const float* __restrict__ A_log,
                 _Float16* __restrict__ h_end, float* __restrict__ dtsum)
{
    const int c = blockIdx.x, b = blockIdx.y, d = threadIdx.x;
    float Av[DS_];
    #pragma unroll
    for (int n = 0; n < DS_; n++) Av[n] = -expf(A_log[d * DS_ + n]);
    float h[DS_] = {};
    float dts = 0.f;
    const int base = b * L_ + c * CH;
    const size_t rbase = (size_t)base * DI_ + d;
    for (int tl = 0; tl < CH; tl++) {
        const float* Br = xdbl32 + (size_t)(base + tl) * 32;   // s_load
        const float dtv = (float)dth[rbase + (size_t)tl * DI_];
        const float xv  = (float)xs[rbase + (size_t)tl * DI_];
        dts += dtv;
        const float dtx = dtv * xv;
        #pragma unroll
        for (int n = 0; n < DS_; n++)
            h[n] = __expf(dtv * Av[n]) * h[n] + dtx * Br[n];
    }
    const size_t o = (size_t)(b * NCH + c) * DI_ + d;
    half8 v0, v1;
    #pragma unroll
    for (int n = 0; n < 8; n++) { v0[n] = (_Float16)h[n]; v1[n] = (_Float16)h[8 + n]; }
    half8* he = (half8*)(h_end + o * DS_);
    he[0] = v0; he[1] = v1;
    dtsum[o] = dts;
}

// ---------------------------------------------------------------------------
// Scan phase 2: sequential combine across chunks (thread=(b,d,n)); fp16 h IO.
// ---------------------------------------------------------------------------
__global__ __launch_bounds__(256)
void scan_phase2(const _Float16* __restrict__ h_end, const float* __restrict__ dtsum,
                 const float* __restrict__ A_log, _Float16* __restrict__ h_start)
{
    const int gid = blockIdx.x * 256 + threadIdx.x;   // B*DI*DS = 65536
    const int n = gid & 15;
    const int d = (gid >> 4) & (DI_ - 1);
    const int b = gid >> 13;
    const float Av = -expf(A_log[d * DS_ + n]);
    float hs = 0.f;
    for (int c = 0; c < NCH; c++) {
        const size_t o = (size_t)(b * NCH + c) * DI_ + d;
        const float e  = __expf(Av * dtsum[o]);
        const float he = (float)h_end[o * DS_ + n];
        h_start[o * DS_ + n] = (_Float16)hs;
        hs = e * hs + he;
    }
}

// ---------------------------------------------------------------------------
// Scan phase 3: replay with incoming h_start (fp16); pre-activated g (fp16);
// emit y fp16.
// ---------------------------------------------------------------------------
__global__ __launch_bounds__(512)
void scan_phase3(const _Float16* __restrict__ dth, const _Float16* __restrict__ xs,
                 const float* __restrict__ xdbl32, const float* __restrict__ A_log,
                 const float* __restrict__ Dv, const _Float16* __restrict__ gbuf,
                 const _Float16* __restrict__ h_start, _Float16* __restrict__ yout)
{
    const int c = blockIdx.x, b = blockIdx.y, d = threadIdx.x;
    float Av[DS_];
    #pragma unroll
    for (int n = 0; n < DS_; n++) Av[n] = -expf(A_log[d * DS_ + n]);
    float h[DS_];
    {
        const half8* hsv = (const half8*)(h_start + ((size_t)(b * NCH + c) * DI_ + d) * DS_);
        const half8 a = hsv[0], bb = hsv[1];
        #pragma unroll
        for (int n = 0; n < 8; n++) { h[n] = (float)a[n]; h[8 + n] = (float)bb[n]; }
    }
    const float Dd = Dv[d];
    const int base = b * L_ + c * CH;
    const size_t rbase = (size_t)base * DI_ + d;
    for (int tl = 0; tl < CH; tl++) {
        const float* Br = xdbl32 + (size_t)(base + tl) * 32;   // s_load
        const size_t off = rbase + (size_t)tl * DI_;
        const float dtv = (float)dth[off];
        const float xv  = (float)xs[off];
        const float g   = (float)gbuf[off];
        const float dtx = dtv * xv;
        float acc = 0.f;
        #pragma unroll
        for (int n = 0; n < DS_; n++) {
            h[n] = __expf(dtv * Av[n]) * h[n] + dtx * Br[n];
            acc += h[n] * Br[16 + n];   // C row = second half of xdbl32 row
        }
        const float yv = acc + xv * Dd;
        yout[off] = (_Float16)(yv * g);
    }
}

// ---------------------------------------------------------------------------
// Final N=1 GEMV
// ---------------------------------------------------------------------------
__global__ __launch_bounds__(256)
void final_dot(const float* __restrict__ h2, const float* __restrict__ w3,
               const float* __restrict__ b3, float* __restrict__ out)
{
    __shared__ float w3s[128];
    const int tid = threadIdx.x;
    if (tid < 128) w3s[tid] = w3[tid];
    __syncthreads();
    const int m = blockIdx.x * 256 + tid;
    float acc = b3[0];
    #pragma unroll 4
    for (int k = 0; k < 128; k++) acc += h2[(size_t)m * 128 + k] * w3s[k];
    out[m] = acc;
}

// ---------------------------------------------------------------------------
extern "C" void kernel_launch(void* const* d_in, const int* in_sizes, int n_in,
                              void* d_out, int out_size, void* d_ws, size_t ws_size,
                              hipStream_t stream)
{
    const float* state      = (const float*)d_in[0];
    const float* in_proj_w  = (const float*)d_in[1];
    const float* conv_w     = (const float*)d_in[2];
    const float* conv_b     = (const float*)d_in[3];
    const float* x_proj_w   = (const float*)d_in[4];
    const float* dt_proj_w  = (const float*)d_in[5];
    const float* dt_proj_b  = (const float*)d_in[6];
    const float* A_log      = (const float*)d_in[7];
    const float* Dp         = (const float*)d_in[8];
    const float* out_proj_w = (const float*)d_in[9];
    const float* w1 = (const float*)d_in[10];
    const float* b1 = (const float*)d_in[11];
    const float* w2 = (const float*)d_in[12];
    const float* b2 = (const float*)d_in[13];
    const float* w3 = (const float*)d_in[14];
    const float* b3 = (const float*)d_in[15];

    float* ws = (float*)d_ws;
    float*    xbuf   = ws;                      // 4,194,304 f (x compact)
    float*    xdbl32 = xbuf + 4194304;          //   262,144 f
    float*    dtr32  = xdbl32 + 262144;         //   131,072 f
    float*    dtsum  = dtr32 + 131072;          //   262,144 f
    float*    h2     = dtsum + 262144;          // 1,048,576 f
    _Float16* gbuf   = (_Float16*)(h2 + 1048576); // 4,194,304 h (silu(z))
    _Float16* xs_h   = gbuf + 4194304;          // 4,194,304 h
    _Float16* dth    = xs_h + 4194304;          // 4,194,304 h
    _Float16* he_h   = dth + 4194304;           // 4,194,304 h
    _Float16* hs_h   = he_h + 4194304;          // 4,194,304 h
    _Float16* y_h    = hs_h + 4194304;          // 4,194,304 h
    _Float16* outb_h = y_h + 4194304;           // 2,097,152 h
    _Float16* h1_h   = outb_h + 2097152;        // 2,097,152 h
    _Float16* w1t    = h1_h + 2097152;          //    65,536 h
    _Float16* w2t    = w1t + 65536;             //    32,768 h

    // 0. MLP weight transpose+convert (small)
    cvtT_f2h<<<dim3(256), 256, 0, stream>>>(w1, w1t, 256, 256);
    cvtT_f2h<<<dim3(128), 256, 0, stream>>>(w2, w2t, 256, 128);

    // 1. in_proj: x -> fp32 xbuf; z -> silu -> fp16 gbuf  (M=8192,N=1024,K=256)
    hgemm_k<2, true, true><<<dim3(M_/128, 1024/128), 256, 0, stream>>>(
        state, DM_, in_proj_w, xbuf, gbuf, DI_, DM_);
    // 2. causal conv + SiLU -> xs fp16
    conv_silu_k<<<dim3(M_*DI_/4/256), 256, 0, stream>>>(xbuf, conv_w, conv_b, xs_h);
    // 3. x_dbl: MFMA fp16, split outputs (dtr32 / xdbl32)
    xproj_k<<<dim3(M_/64), 256, 0, stream>>>(xs_h, x_proj_w, dtr32, xdbl32);
    // 4. dt = softplus(dtr @ dtw^T + b) -> fp16
    dt_k<<<dim3(M_/4), 512, 0, stream>>>(dtr32, dt_proj_w, dt_proj_b, dth);
    // 5-7. chunked selective scan (all-fp16 streams)
    scan_phase1<<<dim3(NCH, B_), 512, 0, stream>>>(
        dth, xs_h, xdbl32, A_log, he_h, dtsum);
    scan_phase2<<<dim3(256), 256, 0, stream>>>(he_h, dtsum, A_log, hs_h);
    scan_phase3<<<dim3(NCH, B_), 512, 0, stream>>>(
        dth, xs_h, xdbl32, A_log, Dp, gbuf, hs_h, y_h);
    // 8. out = y @ out_proj_w^T  (N=256, K=512) -> fp16, 64-tile
    hgemm64_k<0, false, true, true><<<dim3(M_/64, 256/64), 256, 0, stream>>>(
        y_h, DI_, out_proj_w, nullptr, outb_h, DM_, DI_);
    // 9. h1 = relu(out @ w1 + b1)  (N=256, K=256) -> fp16, 64-tile
    hgemm64_k<1, true, true, false><<<dim3(M_/64, 256/64), 256, 0, stream>>>(
        outb_h, DM_, w1t, b1, h1_h, 256, 256);
    // 10. h2 = relu(h1 @ w2 + b2)  (N=128, K=256) -> fp32, 64-tile
    hgemm64_k<1, true, false, false><<<dim3(M_/64, 128/64), 256, 0, stream>>>(
        h1_h, 256, w2t, b2, h2, 128, 256);
    // 11. out = h2 @ w3 + b3  (N=1)
    final_dot<<<dim3(M_/256), 256, 0, stream>>>(h2, w3, b3, (float*)d_out);
}

// Round 10
// 133.516 us; speedup vs baseline: 1.4530x; 1.0662x over previous
//
#include <hip/hip_runtime.h>
#include <cstdint>
#include <cmath>

#define B_   8
#define L_   1024
#define DM_  256
#define DS_  16
#define DC_  4
#define DI_  512
#define DTR_ 16
#define M_   (B_*L_)    // 8192
#define NCH  64         // number of scan chunks
#define CH   16         // chunk length (NCH*CH == L_)

using half8 = __attribute__((ext_vector_type(8))) _Float16;
using half4 = __attribute__((ext_vector_type(4))) _Float16;
using f32x4 = __attribute__((ext_vector_type(4))) float;

// ---------------------------------------------------------------------------
// load 8 contiguous elements as fp16, converting from fp32 if F32
// ---------------------------------------------------------------------------
template<bool F32>
__device__ __forceinline__ half8 load_h8(const void* base, size_t off)
{
    if constexpr (F32) {
        const float* p = (const float*)base + off;
        const float4 a = *reinterpret_cast<const float4*>(p);
        const float4 b = *reinterpret_cast<const float4*>(p + 4);
        half8 h;
        h[0] = (_Float16)a.x; h[1] = (_Float16)a.y;
        h[2] = (_Float16)a.z; h[3] = (_Float16)a.w;
        h[4] = (_Float16)b.x; h[5] = (_Float16)b.y;
        h[6] = (_Float16)b.z; h[7] = (_Float16)b.w;
        return h;
    } else {
        return *reinterpret_cast<const half8*>((const _Float16*)base + off);
    }
}

// ---------------------------------------------------------------------------
// in_proj MFMA GEMM, tile 128x128, BK=64 (4 K-iters at K=256).
// OMODE 2: cols<512 -> fp32 xbuf; cols>=512 -> silu -> fp16 gbuf.
// ---------------------------------------------------------------------------
template<int OMODE, bool A32, bool W32>
__global__ __launch_bounds__(256)
void hgemm_k(const void* __restrict__ A, int lda,
             const void* __restrict__ W,
             void* __restrict__ Cv, void* __restrict__ Cv2, int ldc, int K)
{
    __shared__ _Float16 Ash[128][72];
    __shared__ _Float16 Bsh[128][72];
    const int tid  = threadIdx.x;
    const int lane = tid & 63;
    const int w    = tid >> 6;
    const int wm   = (w >> 1) * 64;
    const int wn   = (w & 1) * 64;
    const int bm   = blockIdx.x * 128;
    const int bn   = blockIdx.y * 128;

    const int fr = lane & 15;
    const int fk = (lane >> 4) * 8;
    const int sr = tid >> 2;           // 0..63
    const int sc = (tid & 3) * 16;     // 0,16,32,48

    f32x4 acc[4][4] = {};

    for (int k0 = 0; k0 < K; k0 += 64) {
        #pragma unroll
        for (int hh = 0; hh < 2; hh++) {
            const int c = sc + hh * 8;
            *reinterpret_cast<half8*>(&Ash[sr][c]) =
                load_h8<A32>(A, (size_t)(bm + sr) * lda + k0 + c);
            *reinterpret_cast<half8*>(&Ash[sr + 64][c]) =
                load_h8<A32>(A, (size_t)(bm + sr + 64) * lda + k0 + c);
            *reinterpret_cast<half8*>(&Bsh[sr][c]) =
                load_h8<W32>(W, (size_t)(bn + sr) * K + k0 + c);
            *reinterpret_cast<half8*>(&Bsh[sr + 64][c]) =
                load_h8<W32>(W, (size_t)(bn + sr + 64) * K + k0 + c);
        }
        __syncthreads();

        #pragma unroll
        for (int kk = 0; kk < 64; kk += 32) {
            half8 af[4], bf[4];
            #pragma unroll
            for (int mf = 0; mf < 4; mf++)
                af[mf] = *reinterpret_cast<const half8*>(&Ash[wm + mf * 16 + fr][kk + fk]);
            #pragma unroll
            for (int nf = 0; nf < 4; nf++)
                bf[nf] = *reinterpret_cast<const half8*>(&Bsh[wn + nf * 16 + fr][kk + fk]);
            #pragma unroll
            for (int mf = 0; mf < 4; mf++)
                #pragma unroll
                for (int nf = 0; nf < 4; nf++)
                    acc[mf][nf] = __builtin_amdgcn_mfma_f32_16x16x32_f16(
                        af[mf], bf[nf], acc[mf][nf], 0, 0, 0);
        }
        __syncthreads();
    }

    const int orow = (lane >> 4) * 4;
    const int ocol = lane & 15;
    const bool zside = (OMODE == 2) && (bn >= DI_);
    #pragma unroll
    for (int mf = 0; mf < 4; mf++) {
        #pragma unroll
        for (int nf = 0; nf < 4; nf++) {
            const int gc = bn + wn + nf * 16 + ocol;
            #pragma unroll
            for (int r = 0; r < 4; r++) {
                const int gr = bm + wm + mf * 16 + orow + r;
                const float v = acc[mf][nf][r];
                if (OMODE == 2) {
                    if (zside) {
                        const float g = v * (1.f / (1.f + __expf(-v)));
                        ((_Float16*)Cv2)[(size_t)gr * DI_ + (gc - DI_)] = (_Float16)g;
                    } else {
                        ((float*)Cv)[(size_t)gr * DI_ + gc] = v;
                    }
                } else {
                    ((float*)Cv)[(size_t)gr * ldc + gc] = v;
                }
            }
        }
    }
}

// ---------------------------------------------------------------------------
// fp16 MFMA GEMM, tile 64x64 (tail GEMMs: out_proj, mlp1, mlp2).
// ---------------------------------------------------------------------------
template<int ACT, bool BIAS, bool OUTH, bool W32>
__global__ __launch_bounds__(256)
void hgemm64_k(const _Float16* __restrict__ A, int lda,
               const void* __restrict__ W,
               const float* __restrict__ bias,
               void* __restrict__ Cv, int ldc, int K)
{
    __shared__ _Float16 Ash[64][40];
    __shared__ _Float16 Bsh[64][40];
    const int tid  = threadIdx.x;
    const int lane = tid & 63;
    const int w    = tid >> 6;
    const int wm   = (w >> 1) * 32;
    const int wn   = (w & 1) * 32;
    const int bm   = blockIdx.x * 64;
    const int bn   = blockIdx.y * 64;

    const int fr = lane & 15;
    const int fk = (lane >> 4) * 8;
    const int sr = tid >> 2;
    const int sg = (tid & 3) * 8;

    f32x4 acc[2][2] = {};

    for (int k0 = 0; k0 < K; k0 += 32) {
        *reinterpret_cast<half8*>(&Ash[sr][sg]) =
            load_h8<false>(A, (size_t)(bm + sr) * lda + k0 + sg);
        *reinterpret_cast<half8*>(&Bsh[sr][sg]) =
            load_h8<W32>(W, (size_t)(bn + sr) * K + k0 + sg);
        __syncthreads();

        half8 af[2], bf[2];
        #pragma unroll
        for (int mf = 0; mf < 2; mf++)
            af[mf] = *reinterpret_cast<const half8*>(&Ash[wm + mf * 16 + fr][fk]);
        #pragma unroll
        for (int nf = 0; nf < 2; nf++)
            bf[nf] = *reinterpret_cast<const half8*>(&Bsh[wn + nf * 16 + fr][fk]);
        #pragma unroll
        for (int mf = 0; mf < 2; mf++)
            #pragma unroll
            for (int nf = 0; nf < 2; nf++)
                acc[mf][nf] = __builtin_amdgcn_mfma_f32_16x16x32_f16(
                    af[mf], bf[nf], acc[mf][nf], 0, 0, 0);
        __syncthreads();
    }

    const int orow = (lane >> 4) * 4;
    const int ocol = lane & 15;
    #pragma unroll
    for (int mf = 0; mf < 2; mf++) {
        #pragma unroll
        for (int nf = 0; nf < 2; nf++) {
            const int gc = bn + wn + nf * 16 + ocol;
            float b = BIAS ? bias[gc] : 0.f;
            #pragma unroll
            for (int r = 0; r < 4; r++) {
                const int gr = bm + wm + mf * 16 + orow + r;
                float v = acc[mf][nf][r] + b;
                if (ACT == 1) v = fmaxf(v, 0.f);
                if (OUTH)
                    ((_Float16*)Cv)[(size_t)gr * ldc + gc] = (_Float16)v;
                else
                    ((float*)Cv)[(size_t)gr * ldc + gc] = v;
            }
        }
    }
}

// ---------------------------------------------------------------------------
// x_proj MFMA kernel: xs (M,512) fp16 -> split x_dbl outputs (fp32).
// ---------------------------------------------------------------------------
__global__ __launch_bounds__(256)
void xproj_k(const _Float16* __restrict__ xs,
             const float* __restrict__ xpw,
             float* __restrict__ dtr32,
             float* __restrict__ xdbl32)
{
    __shared__ _Float16 Ash[64][40];
    __shared__ _Float16 Bsh[48][40];
    const int tid  = threadIdx.x;
    const int lane = tid & 63;
    const int w    = tid >> 6;
    const int bm   = blockIdx.x * 64;
    const int fr   = lane & 15;
    const int fk   = (lane >> 4) * 8;
    const int sr   = tid >> 2;
    const int sg   = (tid & 3) * 8;

    f32x4 acc[3] = {};

    for (int k0 = 0; k0 < 512; k0 += 32) {
        *reinterpret_cast<half8*>(&Ash[sr][sg]) =
            load_h8<false>(xs, (size_t)(bm + sr) * 512 + k0 + sg);
        if (sr < 48)
            *reinterpret_cast<half8*>(&Bsh[sr][sg]) =
                load_h8<true>(xpw, (size_t)sr * 512 + k0 + sg);
        __syncthreads();
        const half8 af = *reinterpret_cast<const half8*>(&Ash[w * 16 + fr][fk]);
        #pragma unroll
        for (int nf = 0; nf < 3; nf++) {
            const half8 bf = *reinterpret_cast<const half8*>(&Bsh[nf * 16 + fr][fk]);
            acc[nf] = __builtin_amdgcn_mfma_f32_16x16x32_f16(af, bf, acc[nf], 0, 0, 0);
        }
        __syncthreads();
    }

    const int orow = (lane >> 4) * 4;
    const int ocol = lane & 15;
    #pragma unroll
    for (int nf = 0; nf < 3; nf++) {
        #pragma unroll
        for (int r = 0; r < 4; r++) {
            const int gr = bm + w * 16 + orow + r;
            const float v = acc[nf][r];
            if (nf == 0)
                dtr32[(size_t)gr * 16 + ocol] = v;
            else
                xdbl32[(size_t)gr * 32 + (nf - 1) * 16 + ocol] = v;
        }
    }
}

// ---------------------------------------------------------------------------
// merged MLP weight transpose+convert: w1 (256x256) then w2 (256x128)
// ---------------------------------------------------------------------------
__global__ __launch_bounds__(256)
void cvtT2_f2h(const float* __restrict__ w1, _Float16* __restrict__ w1t,
               const float* __restrict__ w2, _Float16* __restrict__ w2t)
{
    const int g = blockIdx.x * 256 + threadIdx.x;
    if (g < 65536) {
        const int r = g >> 8, c = g & 255;
        w1t[(size_t)c * 256 + r] = (_Float16)w1[g];
    } else if (g < 98304) {
        const int gg = g - 65536;
        const int r = gg >> 7, c = gg & 127;
        w2t[(size_t)c * 256 + r] = (_Float16)w2[gg];
    }
}

// ---------------------------------------------------------------------------
// dt precompute: dt[t,d] = softplus(dtr[t,:] . dtw[d,:] + dtb[d]) -> fp16.
// ---------------------------------------------------------------------------
__global__ __launch_bounds__(512)
void dt_k(const float* __restrict__ dtr32, const float* __restrict__ dtw,
          const float* __restrict__ dtb, _Float16* __restrict__ dth)
{
    const int d = threadIdx.x;
    const int t0 = blockIdx.x * 4;
    float wreg[DTR_];
    #pragma unroll
    for (int r = 0; r < DTR_; r++) wreg[r] = dtw[d * DTR_ + r];
    const float bd = dtb[d];
    #pragma unroll
    for (int i = 0; i < 4; i++) {
        const float* dr = dtr32 + (size_t)(t0 + i) * 16;   // block-uniform
        float v = bd;
        #pragma unroll
        for (int r = 0; r < DTR_; r++) v += dr[r] * wreg[r];
        const float dtv = (v > 20.f) ? v : __logf(1.f + __expf(v));
        dth[(size_t)(t0 + i) * DI_ + d] = (_Float16)dtv;
    }
}

// ---------------------------------------------------------------------------
// Causal depthwise conv (DC=4 taps) + SiLU; fp32 in (compact), fp16 out.
// ---------------------------------------------------------------------------
__global__ __launch_bounds__(256)
void conv_silu_k(const float* __restrict__ xbuf, const float* __restrict__ cw,
                 const float* __restrict__ cb, _Float16* __restrict__ xs)
{
    const int gid = blockIdx.x * 256 + threadIdx.x;   // 0 .. M_*DI_/4-1
    const int d4  = (gid & 127) << 2;                 // 0,4,..,508
    const int row = gid >> 7;
    const int t   = row & (L_ - 1);
    float4 acc = *reinterpret_cast<const float4*>(cb + d4);
    float4 cwv[4];
    #pragma unroll
    for (int i = 0; i < 4; i++)
        cwv[i] = *reinterpret_cast<const float4*>(cw + (d4 + i) * DC_);
    #pragma unroll
    for (int k = 0; k < DC_; k++) {
        const int tt = t - (DC_ - 1) + k;
        if (tt >= 0) {
            const float4 xv = *reinterpret_cast<const float4*>(
                xbuf + (size_t)(row - (DC_ - 1) + k) * DI_ + d4);
            acc.x += xv.x * ((const float*)&cwv[0])[k];
            acc.y += xv.y * ((const float*)&cwv[1])[k];
            acc.z += xv.z * ((const float*)&cwv[2])[k];
            acc.w += xv.w * ((const float*)&cwv[3])[k];
        }
    }
    half4 o;
    o[0] = (_Float16)(acc.x * (1.f / (1.f + __expf(-acc.x))));
    o[1] = (_Float16)(acc.y * (1.f / (1.f + __expf(-acc.y))));
    o[2] = (_Float16)(acc.z * (1.f / (1.f + __expf(-acc.z))));
    o[3] = (_Float16)(acc.w * (1.f / (1.f + __expf(-acc.w))));
    *reinterpret_cast<half4*>(xs + (size_t)row * DI_ + d4) = o;
}

// ---------------------------------------------------------------------------
// A-structure check: Av[n] ~= (n+1)*Av[0]  (true for A_log=log(arange(1..DS)))
// ---------------------------------------------------------------------------
__device__ __forceinline__ bool a_is_arange(const float* Av)
{
    bool fast = true;
    #pragma unroll
    for (int n = 1; n < DS_; n++)
        fast = fast && (fabsf(Av[n] - (n + 1) * Av[0]) <= 1e-3f * (n + 1));
    return fast;
}

// ---------------------------------------------------------------------------
// Scan phase 1: fp16 dt/xs in, fp16 h_end out; B rows block-uniform (s_load).
// Fast path: dA[n] = e1^(n+1), e1 = exp(dt*Av[0]) -> 1 exp/step.
// ---------------------------------------------------------------------------
__global__ __launch_bounds__(512)
void scan_phase1(const _Float16* __restrict__ dth, const _Float16* __restrict__ xs,
                 const float* __restrict__ xdbl32, const float* __restrict__ A_log,
                 _Float16* __restrict__ h_end, float* __restrict__ dtsum)
{
    const int c = blockIdx.x, b = blockIdx.y, d = threadIdx.x;
    float Av[DS_];
    #pragma unroll
    for (int n = 0; n < DS_; n++) Av[n] = -expf(A_log[d * DS_ + n]);
    float h[DS_] = {};
    float dts = 0.f;
    const int base = b * L_ + c * CH;
    const size_t rbase = (size_t)base * DI_ + d;
    if (a_is_arange(Av)) {
        const float Av0 = Av[0];
        for (int tl = 0; tl < CH; tl++) {
            const float* Br = xdbl32 + (size_t)(base + tl) * 32;   // s_load
            const float dtv = (float)dth[rbase + (size_t)tl * DI_];
            const float xv  = (float)xs[rbase + (size_t)tl * DI_];
            dts += dtv;
            const float dtx = dtv * xv;
            const float e1 = __expf(dtv * Av0);
            float e = 1.f;
            #pragma unroll
            for (int n = 0; n < DS_; n++) {
                e *= e1;
                h[n] = e * h[n] + dtx * Br[n];
            }
        }
    } else {
        for (int tl = 0; tl < CH; tl++) {
            const float* Br = xdbl32 + (size_t)(base + tl) * 32;
            const float dtv = (float)dth[rbase + (size_t)tl * DI_];
            const float xv  = (float)xs[rbase + (size_t)tl * DI_];
            dts += dtv;
            const float dtx = dtv * xv;
            #pragma unroll
            for (int n = 0; n < DS_; n++)
                h[n] = __expf(dtv * Av[n]) * h[n] + dtx * Br[n];
        }
    }
    const size_t o = (size_t)(b * NCH + c) * DI_ + d;
    half8 v0, v1;
    #pragma unroll
    for (int n = 0; n < 8; n++) { v0[n] = (_Float16)h[n]; v1[n] = (_Float16)h[8 + n]; }
    half8* he = (half8*)(h_end + o * DS_);
    he[0] = v0; he[1] = v1;
    dtsum[o] = dts;
}

// ---------------------------------------------------------------------------
// Scan phase 2: sequential combine across chunks (thread=(b,d,n)); fp16 h IO.
// ---------------------------------------------------------------------------
__global__ __launch_bounds__(256)
void scan_phase2(const _Float16* __restrict__ h_end, const float* __restrict__ dtsum,
                 const float* __restrict__ A_log, _Float16* __restrict__ h_start)
{
    const int gid = blockIdx.x * 256 + threadIdx.x;   // B*DI*DS = 65536
    const int n = gid & 15;
    const int d = (gid >> 4) & (DI_ - 1);
    const int b = gid >> 13;
    const float Av = -expf(A_log[d * DS_ + n]);
    float hs = 0.f;
    for (int c = 0; c < NCH; c++) {
        const size_t o = (size_t)(b * NCH + c) * DI_ + d;
        const float e  = __expf(Av * dtsum[o]);
        const float he = (float)h_end[o * DS_ + n];
        h_start[o * DS_ + n] = (_Float16)hs;
        hs = e * hs + he;
    }
}

// ---------------------------------------------------------------------------
// Scan phase 3: replay with incoming h_start (fp16); pre-activated g (fp16);
// emit y fp16.  Fast path as phase 1.
// ---------------------------------------------------------------------------
__global__ __launch_bounds__(512)
void scan_phase3(const _Float16* __restrict__ dth, const _Float16* __restrict__ xs,
                 const float* __restrict__ xdbl32, const float* __restrict__ A_log,
                 const float* __restrict__ Dv, const _Float16* __restrict__ gbuf,
                 const _Float16* __restrict__ h_start, _Float16* __restrict__ yout)
{
    const int c = blockIdx.x, b = blockIdx.y, d = threadIdx.x;
    float Av[DS_];
    #pragma unroll
    for (int n = 0; n < DS_; n++) Av[n] = -expf(A_log[d * DS_ + n]);
    float h[DS_];
    {
        const half8* hsv = (const half8*)(h_start + ((size_t)(b * NCH + c) * DI_ + d) * DS_);
        const half8 a = hsv[0], bb = hsv[1];
        #pragma unroll
        for (int n = 0; n < 8; n++) { h[n] = (float)a[n]; h[8 + n] = (float)bb[n]; }
    }
    const float Dd = Dv[d];
    const int base = b * L_ + c * CH;
    const size_t rbase = (size_t)base * DI_ + d;
    if (a_is_arange(Av)) {
        const float Av0 = Av[0];
        for (int tl = 0; tl < CH; tl++) {
            const float* Br = xdbl32 + (size_t)(base + tl) * 32;   // s_load
            const size_t off = rbase + (size_t)tl * DI_;
            const float dtv = (float)dth[off];
            const float xv  = (float)xs[off];
            const float g   = (float)gbuf[off];
            const float dtx = dtv * xv;
            const float e1 = __expf(dtv * Av0);
            float e = 1.f;
            float acc = 0.f;
            #pragma unroll
            for (int n = 0; n < DS_; n++) {
                e *= e1;
                h[n] = e * h[n] + dtx * Br[n];
                acc += h[n] * Br[16 + n];
            }
            const float yv = acc + xv * Dd;
            yout[off] = (_Float16)(yv * g);
        }
    } else {
        for (int tl = 0; tl < CH; tl++) {
            const float* Br = xdbl32 + (size_t)(base + tl) * 32;
            const size_t off = rbase + (size_t)tl * DI_;
            const float dtv = (float)dth[off];
            const float xv  = (float)xs[off];
            const float g   = (float)gbuf[off];
            const float dtx = dtv * xv;
            float acc = 0.f;
            #pragma unroll
            for (int n = 0; n < DS_; n++) {
                h[n] = __expf(dtv * Av[n]) * h[n] + dtx * Br[n];
                acc += h[n] * Br[16 + n];
            }
            const float yv = acc + xv * Dd;
            yout[off] = (_Float16)(yv * g);
        }
    }
}

// ---------------------------------------------------------------------------
// Final N=1 GEMV
// ---------------------------------------------------------------------------
__global__ __launch_bounds__(256)
void final_dot(const float* __restrict__ h2, const float* __restrict__ w3,
               const float* __restrict__ b3, float* __restrict__ out)
{
    __shared__ float w3s[128];
    const int tid = threadIdx.x;
    if (tid < 128) w3s[tid] = w3[tid];
    __syncthreads();
    const int m = blockIdx.x * 256 + tid;
    float acc = b3[0];
    #pragma unroll 4
    for (int k = 0; k < 128; k++) acc += h2[(size_t)m * 128 + k] * w3s[k];
    out[m] = acc;
}

// ---------------------------------------------------------------------------
extern "C" void kernel_launch(void* const* d_in, const int* in_sizes, int n_in,
                              void* d_out, int out_size, void* d_ws, size_t ws_size,
                              hipStream_t stream)
{
    const float* state      = (const float*)d_in[0];
    const float* in_proj_w  = (const float*)d_in[1];
    const float* conv_w     = (const float*)d_in[2];
    const float* conv_b     = (const float*)d_in[3];
    const float* x_proj_w   = (const float*)d_in[4];
    const float* dt_proj_w  = (const float*)d_in[5];
    const float* dt_proj_b  = (const float*)d_in[6];
    const float* A_log      = (const float*)d_in[7];
    const float* Dp         = (const float*)d_in[8];
    const float* out_proj_w = (const float*)d_in[9];
    const float* w1 = (const float*)d_in[10];
    const float* b1 = (const float*)d_in[11];
    const float* w2 = (const float*)d_in[12];
    const float* b2 = (const float*)d_in[13];
    const float* w3 = (const float*)d_in[14];
    const float* b3 = (const float*)d_in[15];

    float* ws = (float*)d_ws;
    float*    xbuf   = ws;                      // 4,194,304 f (x compact)
    float*    xdbl32 = xbuf + 4194304;          //   262,144 f
    float*    dtr32  = xdbl32 + 262144;         //   131,072 f
    float*    dtsum  = dtr32 + 131072;          //   262,144 f
    float*    h2     = dtsum + 262144;          // 1,048,576 f
    _Float16* gbuf   = (_Float16*)(h2 + 1048576); // 4,194,304 h (silu(z))
    _Float16* xs_h   = gbuf + 4194304;          // 4,194,304 h
    _Float16* dth    = xs_h + 4194304;          // 4,194,304 h
    _Float16* he_h   = dth + 4194304;           // 4,194,304 h
    _Float16* hs_h   = he_h + 4194304;          // 4,194,304 h
    _Float16* y_h    = hs_h + 4194304;          // 4,194,304 h
    _Float16* outb_h = y_h + 4194304;           // 2,097,152 h
    _Float16* h1_h   = outb_h + 2097152;        // 2,097,152 h
    _Float16* w1t    = h1_h + 2097152;          //    65,536 h
    _Float16* w2t    = w1t + 65536;             //    32,768 h

    // 0. MLP weight transpose+convert (merged)
    cvtT2_f2h<<<dim3(384), 256, 0, stream>>>(w1, w1t, w2, w2t);

    // 1. in_proj: x -> fp32 xbuf; z -> silu -> fp16 gbuf  (M=8192,N=1024,K=256)
    hgemm_k<2, true, true><<<dim3(M_/128, 1024/128), 256, 0, stream>>>(
        state, DM_, in_proj_w, xbuf, gbuf, DI_, DM_);
    // 2. causal conv + SiLU -> xs fp16
    conv_silu_k<<<dim3(M_*DI_/4/256), 256, 0, stream>>>(xbuf, conv_w, conv_b, xs_h);
    // 3. x_dbl: MFMA fp16, split outputs (dtr32 / xdbl32)
    xproj_k<<<dim3(M_/64), 256, 0, stream>>>(xs_h, x_proj_w, dtr32, xdbl32);
    // 4. dt = softplus(dtr @ dtw^T + b) -> fp16
    dt_k<<<dim3(M_/4), 512, 0, stream>>>(dtr32, dt_proj_w, dt_proj_b, dth);
    // 5-7. chunked selective scan (all-fp16 streams, 1-exp fast path)
    scan_phase1<<<dim3(NCH, B_), 512, 0, stream>>>(
        dth, xs_h, xdbl32, A_log, he_h, dtsum);
    scan_phase2<<<dim3(256), 256, 0, stream>>>(he_h, dtsum, A_log, hs_h);
    scan_phase3<<<dim3(NCH, B_), 512, 0, stream>>>(
        dth, xs_h, xdbl32, A_log, Dp, gbuf, hs_h, y_h);
    // 8. out = y @ out_proj_w^T  (N=256, K=512) -> fp16, 64-tile
    hgemm64_k<0, false, true, true><<<dim3(M_/64, 256/64), 256, 0, stream>>>(
        y_h, DI_, out_proj_w, nullptr, outb_h, DM_, DI_);
    // 9. h1 = relu(out @ w1 + b1)  (N=256, K=256) -> fp16, 64-tile
    hgemm64_k<1, true, true, false><<<dim3(M_/64, 256/64), 256, 0, stream>>>(
        outb_h, DM_, w1t, b1, h1_h, 256, 256);
    // 10. h2 = relu(h1 @ w2 + b2)  (N=128, K=256) -> fp32, 64-tile
    hgemm64_k<1, true, false, false><<<dim3(M_/64, 128/64), 256, 0, stream>>>(
        h1_h, 256, w2t, b2, h2, 128, 256);
    // 11. out = h2 @ w3 + b3  (N=1)
    final_dot<<<dim3(M_/256), 256, 0, stream>>>(h2, w3, b3, (float*)d_out);
}